// Round 1
// baseline (4295.718 us; speedup 1.0000x reference)
//
#include <hip/hip_runtime.h>
#include <math.h>

#define N_NODES 2048
#define NE      16384
#define NB      64
#define FIN     92
#define DD      128
#define HH_     4
#define CC_     128
#define HC_     512
#define C3_     384
#define NL      5
#define EPSV    1e-5f

struct alignas(16) F4 { float v[4]; };

// ---------------- generic fp32 GEMM: C = act(A@B + bias) ----------------
// A: M x K row-major, B: K x Nc row-major, C: M x Nc. M,Nc multiples of 64.
// act: 0=none, 1=softplus, 2=silu
__global__ __launch_bounds__(256) void gemm_f32(
    const float* __restrict__ A, const float* __restrict__ B,
    const float* __restrict__ bias, float* __restrict__ Cmat,
    int M, int Nc, int K, int act)
{
    __shared__ float As[16][68];
    __shared__ float Bs[16][64];
    const int tx = threadIdx.x & 15, ty = threadIdx.x >> 4;
    const int row0 = blockIdx.y * 64, col0 = blockIdx.x * 64;
    float acc[4][4] = {};
    for (int kb = 0; kb < K; kb += 16) {
        #pragma unroll
        for (int it = 0; it < 4; ++it) {
            int p = threadIdx.x + 256 * it;
            int r = p >> 4, kk = p & 15;
            As[kk][r] = (kb + kk < K) ? A[(size_t)(row0 + r) * K + kb + kk] : 0.f;
        }
        #pragma unroll
        for (int it = 0; it < 4; ++it) {
            int p = threadIdx.x + 256 * it;
            int kk = p >> 6, cc = p & 63;
            Bs[kk][cc] = (kb + kk < K) ? B[(size_t)(kb + kk) * Nc + col0 + cc] : 0.f;
        }
        __syncthreads();
        #pragma unroll
        for (int kk = 0; kk < 16; ++kk) {
            F4 a = *(const F4*)&As[kk][ty * 4];
            F4 b = *(const F4*)&Bs[kk][tx * 4];
            #pragma unroll
            for (int i = 0; i < 4; ++i)
                #pragma unroll
                for (int j = 0; j < 4; ++j)
                    acc[i][j] += a.v[i] * b.v[j];
        }
        __syncthreads();
    }
    #pragma unroll
    for (int i = 0; i < 4; ++i) {
        int r = row0 + ty * 4 + i;
        #pragma unroll
        for (int j = 0; j < 4; ++j) {
            int cc = col0 + tx * 4 + j;
            float v = acc[i][j] + (bias ? bias[cc] : 0.f);
            if (act == 1) v = fmaxf(v, 0.f) + log1pf(expf(-fabsf(v)));
            else if (act == 2) v = v / (1.f + expf(-v));
            Cmat[(size_t)r * Nc + cc] = v;
        }
    }
}

// ---------------- RBF expansion ----------------
__global__ void rbf_kernel(const float* __restrict__ eattr, float* __restrict__ rbf)
{
    int idx = blockIdx.x * 256 + threadIdx.x;
    int e = idx >> 7, c = idx & 127;
    float x0 = eattr[e * 3 + 0], x1 = eattr[e * 3 + 1], x2 = eattr[e * 3 + 2];
    float d = sqrtf(x0 * x0 + x1 * x1 + x2 * x2);
    float ctr = (8.0f / 127.0f) * (float)c;
    float t = d - ctr;
    rbf[idx] = expf(-15.875f * t * t);
}

// ---------------- fused edge kernel ----------------
// Per block: 8 edges x 4 heads = 32 rows.
// alpha -> LN -> sigmoid gate (registers); m_in (LDS) @ wm + bm, *gate -> Ts (LDS);
// Ts @ wmsg + bmsg -> LN -> atomicAdd into agg[dst].
#define EB    8
#define ROWS  32
#define AS_LD 388
#define KCH   16

__global__ __launch_bounds__(256, 2) void edge_kernel(
    const float* __restrict__ q, const float* __restrict__ k, const float* __restrict__ v,
    const float* __restrict__ e, const int* __restrict__ src, const int* __restrict__ dst,
    const float* __restrict__ wm, const float* __restrict__ bm,
    const float* __restrict__ lag, const float* __restrict__ lab,
    const float* __restrict__ wmsg, const float* __restrict__ bmsg,
    const float* __restrict__ lmg, const float* __restrict__ lmb,
    float* __restrict__ agg)
{
    __shared__ float As[ROWS * AS_LD];   // m_in (32 x 384), later reused as Ts
    __shared__ float Bs[KCH * AS_LD];    // weight chunk

    const int tid = threadIdx.x;
    const int tx = tid & 15, ty = tid >> 4;
    const int e0 = blockIdx.x * EB;
    const float ISQ = 0.05103103630798287f;   // 1/sqrt(384)

    // ---- stage m_in = [v_i | v_j | e] into As ----
    #pragma unroll
    for (int it = 0; it < 12; ++it) {
        int p = tid + 256 * it;            // 32 rows * 96 float4
        int row = p / 96, c4 = p % 96;
        int el = row >> 2, hh = row & 3;
        int edge = e0 + el;
        int sec = c4 / 32, cc4 = c4 % 32;
        const float* sp;
        if (sec == 0)      sp = v + (size_t)dst[edge] * HC_ + hh * CC_ + cc4 * 4;
        else if (sec == 1) sp = v + (size_t)src[edge] * HC_ + hh * CC_ + cc4 * 4;
        else               sp = e + (size_t)edge * HC_ + hh * CC_ + cc4 * 4;
        *(F4*)&As[row * AS_LD + c4 * 4] = *(const F4*)sp;
    }

    // ---- gate: alpha -> LN -> sigmoid (in registers) ----
    float gch[2][6][4];
    #pragma unroll
    for (int rr = 0; rr < 2; ++rr) {
        int row = ty + rr * 16;
        int el = row >> 2, hh = row & 3;
        int edge = e0 + el;
        int ni = dst[edge], nj = src[edge];
        const float* qp = q + (size_t)ni * HC_ + hh * CC_;
        const float* kip = k + (size_t)ni * HC_ + hh * CC_;
        const float* kjp = k + (size_t)nj * HC_ + hh * CC_;
        const float* ep  = e + (size_t)edge * HC_ + hh * CC_;
        F4 qi0 = *(const F4*)(qp + tx * 4);
        F4 qi1 = *(const F4*)(qp + tx * 4 + 64);
        F4 ki0 = *(const F4*)(kip + tx * 4);
        F4 ki1 = *(const F4*)(kip + tx * 4 + 64);
        F4 kj0 = *(const F4*)(kjp + tx * 4);
        F4 kj1 = *(const F4*)(kjp + tx * 4 + 64);
        F4 ee0 = *(const F4*)(ep + tx * 4);
        F4 ee1 = *(const F4*)(ep + tx * 4 + 64);
        float a[6][4];
        #pragma unroll
        for (int i = 0; i < 4; ++i) {
            a[0][i] = qi0.v[i] * ki0.v[i] * ISQ;
            a[1][i] = qi1.v[i] * ki1.v[i] * ISQ;
            a[2][i] = qi0.v[i] * kj0.v[i] * ISQ;
            a[3][i] = qi1.v[i] * kj1.v[i] * ISQ;
            a[4][i] = qi0.v[i] * ee0.v[i] * ISQ;
            a[5][i] = qi1.v[i] * ee1.v[i] * ISQ;
        }
        float s1 = 0.f, s2 = 0.f;
        #pragma unroll
        for (int jj = 0; jj < 6; ++jj)
            #pragma unroll
            for (int i = 0; i < 4; ++i) { s1 += a[jj][i]; s2 += a[jj][i] * a[jj][i]; }
        #pragma unroll
        for (int off = 1; off < 16; off <<= 1) {
            s1 += __shfl_xor(s1, off);
            s2 += __shfl_xor(s2, off);
        }
        float mu = s1 * (1.f / 384.f);
        float var = s2 * (1.f / 384.f) - mu * mu;
        float rs = rsqrtf(var + EPSV);
        #pragma unroll
        for (int jj = 0; jj < 6; ++jj) {
            F4 lg = *(const F4*)(lag + tx * 4 + 64 * jj);
            F4 lb = *(const F4*)(lab + tx * 4 + 64 * jj);
            #pragma unroll
            for (int i = 0; i < 4; ++i) {
                float z = (a[jj][i] - mu) * rs * lg.v[i] + lb.v[i];
                gch[rr][jj][i] = 1.f / (1.f + expf(-z));
            }
        }
    }

    // ---- phase 1: t = m_in @ wm (32x384 @ 384x384) ----
    float acc[2][6][4] = {};
    for (int kb = 0; kb < C3_ / KCH; ++kb) {
        __syncthreads();
        #pragma unroll
        for (int it = 0; it < 6; ++it) {
            int p = tid + 256 * it;          // 16 rows * 96 float4
            int kk = p / 96, c4 = p % 96;
            *(F4*)&Bs[kk * AS_LD + c4 * 4] =
                *(const F4*)&wm[(size_t)(kb * KCH + kk) * C3_ + c4 * 4];
        }
        __syncthreads();
        #pragma unroll
        for (int kk = 0; kk < KCH; ++kk) {
            int kg = kb * KCH + kk;
            float a0 = As[ty * AS_LD + kg];
            float a1 = As[(ty + 16) * AS_LD + kg];
            #pragma unroll
            for (int jj = 0; jj < 6; ++jj) {
                F4 b = *(const F4*)&Bs[kk * AS_LD + tx * 4 + 64 * jj];
                #pragma unroll
                for (int i = 0; i < 4; ++i) {
                    acc[0][jj][i] += a0 * b.v[i];
                    acc[1][jj][i] += a1 * b.v[i];
                }
            }
        }
    }
    __syncthreads();

    // ---- epilogue 1: gate, write Ts (reuse As) ----
    #pragma unroll
    for (int rr = 0; rr < 2; ++rr) {
        int row = ty + rr * 16;
        #pragma unroll
        for (int jj = 0; jj < 6; ++jj) {
            F4 t4;
            #pragma unroll
            for (int i = 0; i < 4; ++i) {
                int cc = tx * 4 + 64 * jj + i;
                t4.v[i] = (acc[rr][jj][i] + bm[cc]) * gch[rr][jj][i];
            }
            *(F4*)&As[row * AS_LD + tx * 4 + 64 * jj] = t4;
        }
    }
    __syncthreads();

    // ---- phase 2: u = Ts @ wmsg (32x384 @ 384x128) ----
    float acc2[2][2][4] = {};
    for (int kb = 0; kb < C3_ / KCH; ++kb) {
        __syncthreads();
        #pragma unroll
        for (int it = 0; it < 2; ++it) {
            int p = tid + 256 * it;          // 16 rows * 32 float4
            int kk = p / 32, c4 = p % 32;
            *(F4*)&Bs[kk * 132 + c4 * 4] =
                *(const F4*)&wmsg[(size_t)(kb * KCH + kk) * CC_ + c4 * 4];
        }
        __syncthreads();
        #pragma unroll
        for (int kk = 0; kk < KCH; ++kk) {
            int kg = kb * KCH + kk;
            float a0 = As[ty * AS_LD + kg];
            float a1 = As[(ty + 16) * AS_LD + kg];
            #pragma unroll
            for (int jj = 0; jj < 2; ++jj) {
                F4 b = *(const F4*)&Bs[kk * 132 + tx * 4 + 64 * jj];
                #pragma unroll
                for (int i = 0; i < 4; ++i) {
                    acc2[0][jj][i] += a0 * b.v[i];
                    acc2[1][jj][i] += a1 * b.v[i];
                }
            }
        }
    }

    // ---- epilogue 2: +bmsg, row-LN(128), scatter-add ----
    #pragma unroll
    for (int rr = 0; rr < 2; ++rr) {
        int row = ty + rr * 16;
        int el = row >> 2, hh = row & 3;
        int edge = e0 + el;
        int ni = dst[edge];
        float u[2][4];
        float s1 = 0.f, s2 = 0.f;
        #pragma unroll
        for (int jj = 0; jj < 2; ++jj)
            #pragma unroll
            for (int i = 0; i < 4; ++i) {
                int cc = tx * 4 + 64 * jj + i;
                float x = acc2[rr][jj][i] + bmsg[cc];
                u[jj][i] = x; s1 += x; s2 += x * x;
            }
        #pragma unroll
        for (int off = 1; off < 16; off <<= 1) {
            s1 += __shfl_xor(s1, off);
            s2 += __shfl_xor(s2, off);
        }
        float mu = s1 * (1.f / 128.f);
        float var = s2 * (1.f / 128.f) - mu * mu;
        float rs = rsqrtf(var + EPSV);
        #pragma unroll
        for (int jj = 0; jj < 2; ++jj)
            #pragma unroll
            for (int i = 0; i < 4; ++i) {
                int cc = tx * 4 + 64 * jj + i;
                float msg = (u[jj][i] - mu) * rs * lmg[cc] + lmb[cc];
                atomicAdd(&agg[(size_t)ni * HC_ + hh * CC_ + cc], msg);
            }
    }
}

// ---------------- BN stats over nodes (per channel) ----------------
__global__ void bn_stats_kernel(const float* __restrict__ outb,
                                float* __restrict__ mu, float* __restrict__ rv)
{
    int c = blockIdx.x;
    int tid = threadIdx.x;
    float s = 0.f, s2 = 0.f;
    for (int r = tid; r < N_NODES; r += 256) {
        float x = outb[(size_t)r * CC_ + c];
        s += x; s2 += x * x;
    }
    #pragma unroll
    for (int off = 1; off < 64; off <<= 1) {
        s += __shfl_xor(s, off);
        s2 += __shfl_xor(s2, off);
    }
    __shared__ float ls[8];
    int w = tid >> 6, ln = tid & 63;
    if (ln == 0) { ls[w] = s; ls[4 + w] = s2; }
    __syncthreads();
    if (tid == 0) {
        float S = ls[0] + ls[1] + ls[2] + ls[3];
        float S2 = ls[4] + ls[5] + ls[6] + ls[7];
        float m = S * (1.f / N_NODES);
        float var = S2 * (1.f / N_NODES) - m * m;
        mu[c] = m;
        rv[c] = rsqrtf(var + EPSV);
    }
}

__global__ void bn_apply_kernel(const float* __restrict__ outb, const float* __restrict__ skipb,
                                const float* __restrict__ mu, const float* __restrict__ rv,
                                const float* __restrict__ g, const float* __restrict__ b,
                                float* __restrict__ h)
{
    int idx = blockIdx.x * 256 + threadIdx.x;
    int c = idx & (CC_ - 1);
    float x = (outb[idx] - mu[c]) * rv[c] * g[c] + b[c];
    x = x / (1.f + expf(-x));
    h[idx] = x + skipb[idx];
}

// ---------------- output head + batch correction ----------------
__global__ void head_kernel(const float* __restrict__ feat, const float* __restrict__ fcow,
                            const float* __restrict__ fcob, const int* __restrict__ batch,
                            float* __restrict__ out, float* __restrict__ qa_buf,
                            float* __restrict__ qsum, float* __restrict__ cnt)
{
    int n = blockIdx.x * 256 + threadIdx.x;
    float ea = fcob[0], qa = fcob[1];
    for (int j = 0; j < DD; ++j) {
        float f = feat[(size_t)n * DD + j];
        ea += f * fcow[2 * j];
        qa += f * fcow[2 * j + 1];
    }
    out[2 * n] = ea;
    qa_buf[n] = qa;
    int b = batch[n];
    atomicAdd(&qsum[b], qa);
    atomicAdd(&cnt[b], 1.0f);
}

__global__ void final_kernel(const float* __restrict__ qa_buf, const int* __restrict__ batch,
                             const float* __restrict__ qsum, const float* __restrict__ cnt,
                             float* __restrict__ out)
{
    int n = blockIdx.x * 256 + threadIdx.x;
    int b = batch[n];
    out[2 * n + 1] = qa_buf[n] - qsum[b] / cnt[b];
}

// ---------------- launcher ----------------
extern "C" void kernel_launch(void* const* d_in, const int* in_sizes, int n_in,
                              void* d_out, int out_size, void* d_ws, size_t ws_size,
                              hipStream_t stream)
{
    const float* x         = (const float*)d_in[0];
    const float* edge_attr = (const float*)d_in[1];
    const int*   edge_index= (const int*)d_in[2];
    const int*   batch     = (const int*)d_in[3];
    const float* emb_w = (const float*)d_in[4];
    const float* emb_b = (const float*)d_in[5];
    const float* rbf_w1 = (const float*)d_in[6];
    const float* rbf_b1 = (const float*)d_in[7];
    const float* rbf_w2 = (const float*)d_in[8];
    const float* rbf_b2 = (const float*)d_in[9];
    const float* wq = (const float*)d_in[10];
    const float* bq = (const float*)d_in[11];
    const float* wk = (const float*)d_in[12];
    const float* bk = (const float*)d_in[13];
    const float* wv = (const float*)d_in[14];
    const float* bv = (const float*)d_in[15];
    const float* we = (const float*)d_in[16];
    const float* wcat = (const float*)d_in[17];
    const float* bcat = (const float*)d_in[18];
    const float* wm = (const float*)d_in[19];
    const float* bm = (const float*)d_in[20];
    const float* lag = (const float*)d_in[21];
    const float* lab = (const float*)d_in[22];
    const float* wmsg = (const float*)d_in[23];
    const float* bmsg = (const float*)d_in[24];
    const float* lmg = (const float*)d_in[25];
    const float* lmb = (const float*)d_in[26];
    const float* bn_g = (const float*)d_in[27];
    const float* bn_b = (const float*)d_in[28];
    const float* wskip = (const float*)d_in[29];
    const float* bskip = (const float*)d_in[30];
    const float* fc_w = (const float*)d_in[31];
    const float* fc_b = (const float*)d_in[32];
    const float* fco_w = (const float*)d_in[33];
    const float* fco_b = (const float*)d_in[34];

    const int* src = edge_index;
    const int* dst = edge_index + NE;

    float* W = (float*)d_ws;
    size_t o = 0;
    float* h     = W + o; o += (size_t)N_NODES * DD;
    float* ef    = W + o; o += (size_t)NE * DD;
    float* qb    = W + o; o += (size_t)N_NODES * HC_;
    float* kbuf  = W + o; o += (size_t)N_NODES * HC_;
    float* vbuf  = W + o; o += (size_t)N_NODES * HC_;
    float* ebuf  = W + o; o += (size_t)NE * HC_;
    float* agg   = W + o; o += (size_t)N_NODES * HC_;
    float* outb  = W + o; o += (size_t)N_NODES * CC_;
    float* skipb = W + o; o += (size_t)N_NODES * CC_;
    float* rbfb  = W + o; o += (size_t)NE * DD;
    float* tmpb  = W + o; o += (size_t)NE * DD;
    float* featb = W + o; o += (size_t)N_NODES * DD;
    float* qa_buf= W + o; o += N_NODES;
    float* mu    = W + o; o += CC_;
    float* rv    = W + o; o += CC_;
    float* qsum  = W + o; o += NB;
    float* cnt   = W + o; o += NB;

    // h = x @ emb_w + emb_b
    gemm_f32<<<dim3(2, 32), 256, 0, stream>>>(x, emb_w, emb_b, h, N_NODES, DD, FIN, 0);
    // rbf -> ef
    rbf_kernel<<<(NE * 128) / 256, 256, 0, stream>>>(edge_attr, rbfb);
    gemm_f32<<<dim3(2, NE / 64), 256, 0, stream>>>(rbfb, rbf_w1, rbf_b1, tmpb, NE, DD, DD, 1);
    gemm_f32<<<dim3(2, NE / 64), 256, 0, stream>>>(tmpb, rbf_w2, rbf_b2, ef, NE, DD, DD, 0);

    for (int l = 0; l < NL; ++l) {
        const float* wq_l = wq + (size_t)l * DD * HC_;
        const float* bq_l = bq + (size_t)l * HC_;
        const float* wk_l = wk + (size_t)l * DD * HC_;
        const float* bk_l = bk + (size_t)l * HC_;
        const float* wv_l = wv + (size_t)l * DD * HC_;
        const float* bv_l = bv + (size_t)l * HC_;
        const float* we_l = we + (size_t)l * DD * HC_;
        const float* wcat_l = wcat + (size_t)l * HC_ * CC_;
        const float* bcat_l = bcat + (size_t)l * CC_;
        const float* wm_l = wm + (size_t)l * C3_ * C3_;
        const float* bm_l = bm + (size_t)l * C3_;
        const float* lag_l = lag + (size_t)l * C3_;
        const float* lab_l = lab + (size_t)l * C3_;
        const float* wmsg_l = wmsg + (size_t)l * C3_ * CC_;
        const float* bmsg_l = bmsg + (size_t)l * CC_;
        const float* lmg_l = lmg + (size_t)l * CC_;
        const float* lmb_l = lmb + (size_t)l * CC_;
        const float* bng_l = bn_g + (size_t)l * CC_;
        const float* bnb_l = bn_b + (size_t)l * CC_;
        const float* wskip_l = wskip + (size_t)l * DD * CC_;
        const float* bskip_l = bskip + (size_t)l * CC_;

        gemm_f32<<<dim3(8, 32), 256, 0, stream>>>(h, wq_l, bq_l, qb, N_NODES, HC_, DD, 0);
        gemm_f32<<<dim3(8, 32), 256, 0, stream>>>(h, wk_l, bk_l, kbuf, N_NODES, HC_, DD, 0);
        gemm_f32<<<dim3(8, 32), 256, 0, stream>>>(h, wv_l, bv_l, vbuf, N_NODES, HC_, DD, 0);
        gemm_f32<<<dim3(8, NE / 64), 256, 0, stream>>>(ef, we_l, nullptr, ebuf, NE, HC_, DD, 0);

        hipMemsetAsync(agg, 0, (size_t)N_NODES * HC_ * sizeof(float), stream);
        edge_kernel<<<NE / EB, 256, 0, stream>>>(qb, kbuf, vbuf, ebuf, src, dst,
                                                 wm_l, bm_l, lag_l, lab_l,
                                                 wmsg_l, bmsg_l, lmg_l, lmb_l, agg);

        gemm_f32<<<dim3(2, 32), 256, 0, stream>>>(agg, wcat_l, bcat_l, outb, N_NODES, CC_, HC_, 0);
        bn_stats_kernel<<<CC_, 256, 0, stream>>>(outb, mu, rv);
        gemm_f32<<<dim3(2, 32), 256, 0, stream>>>(h, wskip_l, bskip_l, skipb, N_NODES, CC_, DD, 0);
        bn_apply_kernel<<<(N_NODES * CC_) / 256, 256, 0, stream>>>(outb, skipb, mu, rv, bng_l, bnb_l, h);
    }

    gemm_f32<<<dim3(2, 32), 256, 0, stream>>>(h, fc_w, fc_b, featb, N_NODES, DD, DD, 2);

    hipMemsetAsync(qsum, 0, (size_t)NB * 2 * sizeof(float), stream);
    head_kernel<<<N_NODES / 256, 256, 0, stream>>>(featb, fco_w, fco_b, batch,
                                                   (float*)d_out, qa_buf, qsum, cnt);
    final_kernel<<<N_NODES / 256, 256, 0, stream>>>(qa_buf, batch, qsum, cnt, (float*)d_out);
}

// Round 2
// 1668.453 us; speedup vs baseline: 2.5747x; 2.5747x over previous
//
#include <hip/hip_runtime.h>
#include <math.h>

#define N_NODES 2048
#define NE      16384
#define NB      64
#define FIN     92
#define DD      128
#define HH_     4
#define CC_     128
#define HC_     512
#define C3_     384
#define NL      5
#define EPSV    1e-5f

struct alignas(16) F4 { float v[4]; };
typedef _Float16 f16x8 __attribute__((ext_vector_type(8)));
typedef float f32x4 __attribute__((ext_vector_type(4)));

// ---------------- generic fp32 GEMM: C = act(A@B + bias) ----------------
__global__ __launch_bounds__(256) void gemm_f32(
    const float* __restrict__ A, const float* __restrict__ B,
    const float* __restrict__ bias, float* __restrict__ Cmat,
    int M, int Nc, int K, int act)
{
    __shared__ float As[16][68];
    __shared__ float Bs[16][64];
    const int tx = threadIdx.x & 15, ty = threadIdx.x >> 4;
    const int row0 = blockIdx.y * 64, col0 = blockIdx.x * 64;
    float acc[4][4] = {};
    for (int kb = 0; kb < K; kb += 16) {
        #pragma unroll
        for (int it = 0; it < 4; ++it) {
            int p = threadIdx.x + 256 * it;
            int r = p >> 4, kk = p & 15;
            As[kk][r] = (kb + kk < K) ? A[(size_t)(row0 + r) * K + kb + kk] : 0.f;
        }
        #pragma unroll
        for (int it = 0; it < 4; ++it) {
            int p = threadIdx.x + 256 * it;
            int kk = p >> 6, cc = p & 63;
            Bs[kk][cc] = (kb + kk < K) ? B[(size_t)(kb + kk) * Nc + col0 + cc] : 0.f;
        }
        __syncthreads();
        #pragma unroll
        for (int kk = 0; kk < 16; ++kk) {
            F4 a = *(const F4*)&As[kk][ty * 4];
            F4 b = *(const F4*)&Bs[kk][tx * 4];
            #pragma unroll
            for (int i = 0; i < 4; ++i)
                #pragma unroll
                for (int j = 0; j < 4; ++j)
                    acc[i][j] += a.v[i] * b.v[j];
        }
        __syncthreads();
    }
    #pragma unroll
    for (int i = 0; i < 4; ++i) {
        int r = row0 + ty * 4 + i;
        #pragma unroll
        for (int j = 0; j < 4; ++j) {
            int cc = col0 + tx * 4 + j;
            float v = acc[i][j] + (bias ? bias[cc] : 0.f);
            if (act == 1) v = fmaxf(v, 0.f) + log1pf(expf(-fabsf(v)));
            else if (act == 2) v = v / (1.f + expf(-v));
            Cmat[(size_t)r * Nc + cc] = v;
        }
    }
}

// ---------------- RBF expansion ----------------
__global__ void rbf_kernel(const float* __restrict__ eattr, float* __restrict__ rbf)
{
    int idx = blockIdx.x * 256 + threadIdx.x;
    int e = idx >> 7, c = idx & 127;
    float x0 = eattr[e * 3 + 0], x1 = eattr[e * 3 + 1], x2 = eattr[e * 3 + 2];
    float d = sqrtf(x0 * x0 + x1 * x1 + x2 * x2);
    float ctr = (8.0f / 127.0f) * (float)c;
    float t = d - ctr;
    rbf[idx] = expf(-15.875f * t * t);
}

// ---------------- per-layer weight transpose+convert to fp16 ----------------
// wmT[n][k]=wm[k][n] (384x384), wmsgT[n][k]=wmsg[k][n] (128x384), weT[n][k]=we[k][n] (512x128)
__global__ void convw_kernel(const float* __restrict__ wm_l, const float* __restrict__ wmsg_l,
                             const float* __restrict__ we_l,
                             _Float16* __restrict__ wmT, _Float16* __restrict__ wmsgT,
                             _Float16* __restrict__ weT)
{
    int idx = blockIdx.x * 256 + threadIdx.x;
    if (idx < 384 * 384) {
        int n = idx / 384, kk = idx % 384;
        wmT[idx] = (_Float16)wm_l[kk * 384 + n];
    } else if (idx < 384 * 384 + 128 * 384) {
        int t = idx - 384 * 384;
        int n = t / 384, kk = t % 384;
        wmsgT[t] = (_Float16)wmsg_l[kk * 128 + n];
    } else if (idx < 384 * 384 + 128 * 384 + 512 * 128) {
        int t = idx - 384 * 384 - 128 * 384;
        int n = t / 128, kk = t % 128;
        weT[t] = (_Float16)we_l[kk * 512 + n];
    }
}

// ---------------- fp16 MFMA GEMM, K=128 fixed ----------------
// C[row][col] = sum_k A[row][k] * Bt[col][bkoff+k]   (A stride = 128)
// tile 128x128, 4 waves, wave = 32 rows x 128 cols, 16x16x32 MFMA
template<bool A_F32>
__global__ __launch_bounds__(256) void gemm_f16k128(
    const void* __restrict__ Av, const _Float16* __restrict__ Bt, int ldb, int bkoff,
    _Float16* __restrict__ Cmat, int ldc)
{
    __shared__ alignas(16) _Float16 As[128 * 40];
    __shared__ alignas(16) _Float16 Bs[128 * 40];
    const int tid = threadIdx.x;
    const int w = tid >> 6, l = tid & 63;
    const int g = l >> 4, c = l & 15;
    const int row0 = blockIdx.x * 128;
    const int col0 = blockIdx.y * 128;
    f32x4 acc[2][8] = {};
    for (int kb = 0; kb < 4; ++kb) {
        __syncthreads();
        #pragma unroll
        for (int i = 0; i < 2; ++i) {
            int p = tid + 256 * i;
            int r = p >> 2, q = p & 3;
            *(uint4*)&Bs[r * 40 + q * 8] =
                *(const uint4*)&Bt[(size_t)(col0 + r) * ldb + bkoff + kb * 32 + q * 8];
            if (A_F32) {
                const float* Af = (const float*)Av;
                const float* ap = Af + (size_t)(row0 + r) * 128 + kb * 32 + q * 8;
                F4 x0 = *(const F4*)ap;
                F4 x1 = *(const F4*)(ap + 4);
                union { _Float16 h[8]; uint4 u; } cv;
                #pragma unroll
                for (int j = 0; j < 4; ++j) { cv.h[j] = (_Float16)x0.v[j]; cv.h[4 + j] = (_Float16)x1.v[j]; }
                *(uint4*)&As[r * 40 + q * 8] = cv.u;
            } else {
                const _Float16* Ah = (const _Float16*)Av;
                *(uint4*)&As[r * 40 + q * 8] =
                    *(const uint4*)&Ah[(size_t)(row0 + r) * 128 + kb * 32 + q * 8];
            }
        }
        __syncthreads();
        f16x8 af[2], bf[8];
        #pragma unroll
        for (int mi = 0; mi < 2; ++mi)
            af[mi] = *(const f16x8*)&As[(w * 32 + mi * 16 + c) * 40 + g * 8];
        #pragma unroll
        for (int ni = 0; ni < 8; ++ni)
            bf[ni] = *(const f16x8*)&Bs[(ni * 16 + c) * 40 + g * 8];
        #pragma unroll
        for (int mi = 0; mi < 2; ++mi)
            #pragma unroll
            for (int ni = 0; ni < 8; ++ni)
                acc[mi][ni] = __builtin_amdgcn_mfma_f32_16x16x32_f16(af[mi], bf[ni], acc[mi][ni], 0, 0, 0);
    }
    #pragma unroll
    for (int mi = 0; mi < 2; ++mi)
        #pragma unroll
        for (int ni = 0; ni < 8; ++ni)
            #pragma unroll
            for (int i = 0; i < 4; ++i) {
                int row = row0 + w * 32 + mi * 16 + g * 4 + i;
                int col = col0 + ni * 16 + c;
                Cmat[(size_t)row * ldc + col] = (_Float16)acc[mi][ni][i];
            }
}

// ---------------- combine: t = (P1[dst]+P2[src]+P3+bm) * sigmoid(LN(alpha)) ----------------
// one wave per edge-head row
__global__ __launch_bounds__(256) void combine_kernel(
    const float* __restrict__ q, const float* __restrict__ k,
    const _Float16* __restrict__ e16,
    const _Float16* __restrict__ p12, const _Float16* __restrict__ p3,
    const float* __restrict__ bm, const float* __restrict__ lag, const float* __restrict__ lab,
    const int* __restrict__ src, const int* __restrict__ dst,
    _Float16* __restrict__ T)
{
    const int w = threadIdx.x >> 6, l = threadIdx.x & 63;
    const int r = blockIdx.x * 4 + w;
    const int edge = r >> 2, hh = r & 3;
    const int ni = dst[edge], nj = src[edge];
    const float* qp  = q + (size_t)ni * HC_ + hh * CC_;
    const float* kip = k + (size_t)ni * HC_ + hh * CC_;
    const float* kjp = k + (size_t)nj * HC_ + hh * CC_;
    const _Float16* ep = e16 + (size_t)r * CC_;
    const int c2 = l * 2;
    const float ISQ = 0.05103103630798287f; // 1/sqrt(384)
    float q0 = qp[c2], q1 = qp[c2 + 1];
    float a[3][2];
    a[0][0] = q0 * kip[c2] * ISQ;        a[0][1] = q1 * kip[c2 + 1] * ISQ;
    a[1][0] = q0 * kjp[c2] * ISQ;        a[1][1] = q1 * kjp[c2 + 1] * ISQ;
    a[2][0] = q0 * (float)ep[c2] * ISQ;  a[2][1] = q1 * (float)ep[c2 + 1] * ISQ;
    float s1 = 0.f, s2 = 0.f;
    #pragma unroll
    for (int s = 0; s < 3; ++s)
        #pragma unroll
        for (int i = 0; i < 2; ++i) { s1 += a[s][i]; s2 += a[s][i] * a[s][i]; }
    #pragma unroll
    for (int off = 1; off < 64; off <<= 1) {
        s1 += __shfl_xor(s1, off);
        s2 += __shfl_xor(s2, off);
    }
    float mu = s1 * (1.f / 384.f);
    float var = s2 * (1.f / 384.f) - mu * mu;
    float rs = rsqrtf(var + EPSV);
    const _Float16* p1p = p12 + (size_t)(ni * 4 + hh) * C3_;
    const _Float16* p2p = p12 + (size_t)8192 * C3_ + (size_t)(nj * 4 + hh) * C3_;
    const _Float16* p3p = p3 + (size_t)r * C3_;
    _Float16* tp = T + (size_t)r * C3_;
    #pragma unroll
    for (int s = 0; s < 3; ++s) {
        #pragma unroll
        for (int i = 0; i < 2; ++i) {
            int col = s * 128 + c2 + i;
            float z = (a[s][i] - mu) * rs * lag[col] + lab[col];
            float gate = 1.f / (1.f + expf(-z));
            float t = (float)p1p[col] + (float)p2p[col] + (float)p3p[col] + bm[col];
            tp[col] = (_Float16)(t * gate);
        }
    }
}

// ---------------- GEMM2: u = T @ wmsg + bmsg; row-LN(128); scatter-add ----------------
// M=65536, N=128, K=384. A = T fp16 (stride 384), Bt = wmsgT [128][384].
__global__ __launch_bounds__(256) void gemm2_f16(
    const _Float16* __restrict__ A, const _Float16* __restrict__ Bt,
    const float* __restrict__ bmsg, const float* __restrict__ lmg, const float* __restrict__ lmb,
    const int* __restrict__ dst, float* __restrict__ agg)
{
    __shared__ alignas(16) _Float16 As[128 * 40];
    __shared__ alignas(16) _Float16 Bs[128 * 40];
    const int tid = threadIdx.x;
    const int w = tid >> 6, l = tid & 63;
    const int g = l >> 4, c = l & 15;
    const int row0 = blockIdx.x * 128;
    f32x4 acc[2][8] = {};
    for (int kb = 0; kb < 12; ++kb) {
        __syncthreads();
        #pragma unroll
        for (int i = 0; i < 2; ++i) {
            int p = tid + 256 * i;
            int r = p >> 2, q = p & 3;
            *(uint4*)&Bs[r * 40 + q * 8] =
                *(const uint4*)&Bt[(size_t)r * 384 + kb * 32 + q * 8];
            *(uint4*)&As[r * 40 + q * 8] =
                *(const uint4*)&A[(size_t)(row0 + r) * 384 + kb * 32 + q * 8];
        }
        __syncthreads();
        f16x8 af[2], bf[8];
        #pragma unroll
        for (int mi = 0; mi < 2; ++mi)
            af[mi] = *(const f16x8*)&As[(w * 32 + mi * 16 + c) * 40 + g * 8];
        #pragma unroll
        for (int ni = 0; ni < 8; ++ni)
            bf[ni] = *(const f16x8*)&Bs[(ni * 16 + c) * 40 + g * 8];
        #pragma unroll
        for (int mi = 0; mi < 2; ++mi)
            #pragma unroll
            for (int ni = 0; ni < 8; ++ni)
                acc[mi][ni] = __builtin_amdgcn_mfma_f32_16x16x32_f16(af[mi], bf[ni], acc[mi][ni], 0, 0, 0);
    }
    float bz[8], lgv[8], lbv[8];
    #pragma unroll
    for (int ni = 0; ni < 8; ++ni) {
        int colc = ni * 16 + c;
        bz[ni] = bmsg[colc]; lgv[ni] = lmg[colc]; lbv[ni] = lmb[colc];
    }
    #pragma unroll
    for (int mi = 0; mi < 2; ++mi)
        #pragma unroll
        for (int i = 0; i < 4; ++i) {
            float u[8];
            float s1 = 0.f, s2 = 0.f;
            #pragma unroll
            for (int ni = 0; ni < 8; ++ni) {
                u[ni] = acc[mi][ni][i] + bz[ni];
                s1 += u[ni]; s2 += u[ni] * u[ni];
            }
            #pragma unroll
            for (int off = 1; off < 16; off <<= 1) {
                s1 += __shfl_xor(s1, off);
                s2 += __shfl_xor(s2, off);
            }
            float mu = s1 * (1.f / 128.f);
            float var = s2 * (1.f / 128.f) - mu * mu;
            float rs = rsqrtf(var + EPSV);
            int grow = row0 + w * 32 + mi * 16 + g * 4 + i;
            int edge = grow >> 2, hh = grow & 3;
            int nd = dst[edge];
            float* ap = agg + (size_t)nd * HC_ + hh * CC_;
            #pragma unroll
            for (int ni = 0; ni < 8; ++ni) {
                int colc = ni * 16 + c;
                float msg = (u[ni] - mu) * rs * lgv[ni] + lbv[ni];
                atomicAdd(ap + colc, msg);
            }
        }
}

// ---------------- BN stats over nodes (per channel) ----------------
__global__ void bn_stats_kernel(const float* __restrict__ outb,
                                float* __restrict__ mu, float* __restrict__ rv)
{
    int c = blockIdx.x;
    int tid = threadIdx.x;
    float s = 0.f, s2 = 0.f;
    for (int r = tid; r < N_NODES; r += 256) {
        float x = outb[(size_t)r * CC_ + c];
        s += x; s2 += x * x;
    }
    #pragma unroll
    for (int off = 1; off < 64; off <<= 1) {
        s += __shfl_xor(s, off);
        s2 += __shfl_xor(s2, off);
    }
    __shared__ float ls[8];
    int w = tid >> 6, ln = tid & 63;
    if (ln == 0) { ls[w] = s; ls[4 + w] = s2; }
    __syncthreads();
    if (tid == 0) {
        float S = ls[0] + ls[1] + ls[2] + ls[3];
        float S2 = ls[4] + ls[5] + ls[6] + ls[7];
        float m = S * (1.f / N_NODES);
        float var = S2 * (1.f / N_NODES) - m * m;
        mu[c] = m;
        rv[c] = rsqrtf(var + EPSV);
    }
}

__global__ void bn_apply_kernel(const float* __restrict__ outb, const float* __restrict__ skipb,
                                const float* __restrict__ mu, const float* __restrict__ rv,
                                const float* __restrict__ g, const float* __restrict__ b,
                                float* __restrict__ h)
{
    int idx = blockIdx.x * 256 + threadIdx.x;
    int c = idx & (CC_ - 1);
    float x = (outb[idx] - mu[c]) * rv[c] * g[c] + b[c];
    x = x / (1.f + expf(-x));
    h[idx] = x + skipb[idx];
}

// ---------------- output head + batch correction ----------------
__global__ void head_kernel(const float* __restrict__ feat, const float* __restrict__ fcow,
                            const float* __restrict__ fcob, const int* __restrict__ batch,
                            float* __restrict__ out, float* __restrict__ qa_buf,
                            float* __restrict__ qsum, float* __restrict__ cnt)
{
    int n = blockIdx.x * 256 + threadIdx.x;
    float ea = fcob[0], qa = fcob[1];
    for (int j = 0; j < DD; ++j) {
        float f = feat[(size_t)n * DD + j];
        ea += f * fcow[2 * j];
        qa += f * fcow[2 * j + 1];
    }
    out[2 * n] = ea;
    qa_buf[n] = qa;
    int b = batch[n];
    atomicAdd(&qsum[b], qa);
    atomicAdd(&cnt[b], 1.0f);
}

__global__ void final_kernel(const float* __restrict__ qa_buf, const int* __restrict__ batch,
                             const float* __restrict__ qsum, const float* __restrict__ cnt,
                             float* __restrict__ out)
{
    int n = blockIdx.x * 256 + threadIdx.x;
    int b = batch[n];
    out[2 * n + 1] = qa_buf[n] - qsum[b] / cnt[b];
}

// ---------------- launcher ----------------
extern "C" void kernel_launch(void* const* d_in, const int* in_sizes, int n_in,
                              void* d_out, int out_size, void* d_ws, size_t ws_size,
                              hipStream_t stream)
{
    const float* x         = (const float*)d_in[0];
    const float* edge_attr = (const float*)d_in[1];
    const int*   edge_index= (const int*)d_in[2];
    const int*   batch     = (const int*)d_in[3];
    const float* emb_w = (const float*)d_in[4];
    const float* emb_b = (const float*)d_in[5];
    const float* rbf_w1 = (const float*)d_in[6];
    const float* rbf_b1 = (const float*)d_in[7];
    const float* rbf_w2 = (const float*)d_in[8];
    const float* rbf_b2 = (const float*)d_in[9];
    const float* wq = (const float*)d_in[10];
    const float* bq = (const float*)d_in[11];
    const float* wk = (const float*)d_in[12];
    const float* bk = (const float*)d_in[13];
    const float* wv = (const float*)d_in[14];
    const float* bv = (const float*)d_in[15];
    const float* we = (const float*)d_in[16];
    const float* wcat = (const float*)d_in[17];
    const float* bcat = (const float*)d_in[18];
    const float* wm = (const float*)d_in[19];
    const float* bm = (const float*)d_in[20];
    const float* lag = (const float*)d_in[21];
    const float* lab = (const float*)d_in[22];
    const float* wmsg = (const float*)d_in[23];
    const float* bmsg = (const float*)d_in[24];
    const float* lmg = (const float*)d_in[25];
    const float* lmb = (const float*)d_in[26];
    const float* bn_g = (const float*)d_in[27];
    const float* bn_b = (const float*)d_in[28];
    const float* wskip = (const float*)d_in[29];
    const float* bskip = (const float*)d_in[30];
    const float* fc_w = (const float*)d_in[31];
    const float* fc_b = (const float*)d_in[32];
    const float* fco_w = (const float*)d_in[33];
    const float* fco_b = (const float*)d_in[34];

    const int* src = edge_index;
    const int* dst = edge_index + NE;

    char* base = (char*)d_ws;
    size_t off = 0;
    auto alloc = [&](size_t bytes) -> char* {
        char* p = base + off;
        off += (bytes + 255) & ~(size_t)255;
        return p;
    };
    float* h      = (float*)alloc((size_t)N_NODES * DD * 4);
    float* ef     = (float*)alloc((size_t)NE * DD * 4);
    float* qb     = (float*)alloc((size_t)N_NODES * HC_ * 4);
    float* kbuf   = (float*)alloc((size_t)N_NODES * HC_ * 4);
    float* vbuf   = (float*)alloc((size_t)N_NODES * HC_ * 4);
    float* agg    = (float*)alloc((size_t)N_NODES * HC_ * 4);
    float* outb   = (float*)alloc((size_t)N_NODES * CC_ * 4);
    float* skipb  = (float*)alloc((size_t)N_NODES * CC_ * 4);
    float* rbfb   = (float*)alloc((size_t)NE * DD * 4);
    float* tmpb   = (float*)alloc((size_t)NE * DD * 4);
    float* featb  = (float*)alloc((size_t)N_NODES * DD * 4);
    float* qa_buf = (float*)alloc((size_t)N_NODES * 4);
    float* mu     = (float*)alloc(CC_ * 4);
    float* rv     = (float*)alloc(CC_ * 4);
    float* qsum   = (float*)alloc((size_t)NB * 2 * 4);   // qsum + cnt contiguous
    float* cnt    = qsum + NB;
    _Float16* ebuf16  = (_Float16*)alloc((size_t)NE * HC_ * 2);
    _Float16* wmT16   = (_Float16*)alloc((size_t)384 * 384 * 2);
    _Float16* wmsgT16 = (_Float16*)alloc((size_t)128 * 384 * 2);
    _Float16* weT16   = (_Float16*)alloc((size_t)512 * 128 * 2);
    _Float16* p12     = (_Float16*)alloc((size_t)2 * 8192 * C3_ * 2);
    _Float16* p3      = (_Float16*)alloc((size_t)NE * HH_ * C3_ * 2);
    _Float16* t16     = (_Float16*)alloc((size_t)NE * HH_ * C3_ * 2);

    // ---- preamble: h = x@emb + b; ef = softplus(rbf@w1+b1)@w2+b2 ----
    gemm_f32<<<dim3(2, 32), 256, 0, stream>>>(x, emb_w, emb_b, h, N_NODES, DD, FIN, 0);
    rbf_kernel<<<(NE * 128) / 256, 256, 0, stream>>>(edge_attr, rbfb);
    gemm_f32<<<dim3(2, NE / 64), 256, 0, stream>>>(rbfb, rbf_w1, rbf_b1, tmpb, NE, DD, DD, 1);
    gemm_f32<<<dim3(2, NE / 64), 256, 0, stream>>>(tmpb, rbf_w2, rbf_b2, ef, NE, DD, DD, 0);

    for (int l = 0; l < NL; ++l) {
        const float* wq_l = wq + (size_t)l * DD * HC_;
        const float* bq_l = bq + (size_t)l * HC_;
        const float* wk_l = wk + (size_t)l * DD * HC_;
        const float* bk_l = bk + (size_t)l * HC_;
        const float* wv_l = wv + (size_t)l * DD * HC_;
        const float* bv_l = bv + (size_t)l * HC_;
        const float* we_l = we + (size_t)l * DD * HC_;
        const float* wcat_l = wcat + (size_t)l * HC_ * CC_;
        const float* bcat_l = bcat + (size_t)l * CC_;
        const float* wm_l = wm + (size_t)l * C3_ * C3_;
        const float* bm_l = bm + (size_t)l * C3_;
        const float* lag_l = lag + (size_t)l * C3_;
        const float* lab_l = lab + (size_t)l * C3_;
        const float* wmsg_l = wmsg + (size_t)l * C3_ * CC_;
        const float* bmsg_l = bmsg + (size_t)l * CC_;
        const float* lmg_l = lmg + (size_t)l * CC_;
        const float* lmb_l = lmb + (size_t)l * CC_;
        const float* bng_l = bn_g + (size_t)l * CC_;
        const float* bnb_l = bn_b + (size_t)l * CC_;
        const float* wskip_l = wskip + (size_t)l * DD * CC_;
        const float* bskip_l = bskip + (size_t)l * CC_;

        // qkv (fp32)
        gemm_f32<<<dim3(8, 32), 256, 0, stream>>>(h, wq_l, bq_l, qb, N_NODES, HC_, DD, 0);
        gemm_f32<<<dim3(8, 32), 256, 0, stream>>>(h, wk_l, bk_l, kbuf, N_NODES, HC_, DD, 0);
        gemm_f32<<<dim3(8, 32), 256, 0, stream>>>(h, wv_l, bv_l, vbuf, N_NODES, HC_, DD, 0);

        // fp16 weight transposes
        convw_kernel<<<1024, 256, 0, stream>>>(wm_l, wmsg_l, we_l, wmT16, wmsgT16, weT16);

        // e = ef @ we  (fp16 MFMA, f32 A inline-converted)
        gemm_f16k128<true><<<dim3(NE / 128, 4), 256, 0, stream>>>(
            ef, weT16, 128, 0, ebuf16, HC_);

        // P1 = v@wm[0:128], P2 = v@wm[128:256]   (M=8192, K=128, N=384)
        gemm_f16k128<true><<<dim3(8192 / 128, 3), 256, 0, stream>>>(
            vbuf, wmT16, 384, 0, p12, C3_);
        gemm_f16k128<true><<<dim3(8192 / 128, 3), 256, 0, stream>>>(
            vbuf, wmT16, 384, 128, p12 + (size_t)8192 * C3_, C3_);

        // P3 = e @ wm[256:384]   (M=65536, K=128, N=384)
        gemm_f16k128<false><<<dim3(NE * HH_ / 128, 3), 256, 0, stream>>>(
            ebuf16, wmT16, 384, 256, p3, C3_);

        // t = (P1[dst]+P2[src]+P3+bm) * sigmoid(LN(alpha))
        combine_kernel<<<NE * HH_ / 4, 256, 0, stream>>>(
            qb, kbuf, ebuf16, p12, p3, bm_l, lag_l, lab_l, src, dst, t16);

        // agg = segment_sum(LN(t@wmsg+bmsg))
        hipMemsetAsync(agg, 0, (size_t)N_NODES * HC_ * sizeof(float), stream);
        gemm2_f16<<<NE * HH_ / 128, 256, 0, stream>>>(
            t16, wmsgT16, bmsg_l, lmg_l, lmb_l, dst, agg);

        // out = agg@wcat+bcat; BN; silu; +h@wskip+bskip
        gemm_f32<<<dim3(2, 32), 256, 0, stream>>>(agg, wcat_l, bcat_l, outb, N_NODES, CC_, HC_, 0);
        bn_stats_kernel<<<CC_, 256, 0, stream>>>(outb, mu, rv);
        gemm_f32<<<dim3(2, 32), 256, 0, stream>>>(h, wskip_l, bskip_l, skipb, N_NODES, CC_, DD, 0);
        bn_apply_kernel<<<(N_NODES * CC_) / 256, 256, 0, stream>>>(outb, skipb, mu, rv, bng_l, bnb_l, h);
    }

    gemm_f32<<<dim3(2, 32), 256, 0, stream>>>(h, fc_w, fc_b, featb, N_NODES, DD, DD, 2);

    hipMemsetAsync(qsum, 0, (size_t)NB * 2 * sizeof(float), stream);
    head_kernel<<<N_NODES / 256, 256, 0, stream>>>(featb, fco_w, fco_b, batch,
                                                   (float*)d_out, qa_buf, qsum, cnt);
    final_kernel<<<N_NODES / 256, 256, 0, stream>>>(qa_buf, batch, qsum, cnt, (float*)d_out);
}

// Round 5
// 1148.405 us; speedup vs baseline: 3.7406x; 1.4528x over previous
//
#include <hip/hip_runtime.h>
#include <math.h>

#define N_NODES 2048
#define NE      16384
#define NB      64
#define FIN     92
#define DD      128
#define HH_     4
#define CC_     128
#define HC_     512
#define C3_     384
#define NL      5
#define EPSV    1e-5f

// per-layer packed fp16 weight block offsets (halves)
#define LWH        540672
#define OFF_QKVST  0        // [1664][128]
#define OFF_W12T   212992   // [768][128]
#define OFF_WM3T   311296   // [384][128]
#define OFF_WMSGT  360448   // [128][384]
#define OFF_WET    409600   // [512][128]
#define OFF_WCATT  475136   // [128][512]
#define EX0        (5*LWH)
#define OFF_EMBT   (EX0)            // [128][96]
#define OFF_W1T    (EX0+12288)      // [128][128]
#define OFF_W2T    (EX0+28672)      // [128][128]
#define OFF_FCT    (EX0+45056)      // [128][128]
#define TOT_H      (EX0+61440)
#define TOT_ALL    (TOT_H + 5*1664)

struct alignas(16) F4 { float v[4]; };
typedef _Float16 f16x8 __attribute__((ext_vector_type(8)));
typedef float f32x4 __attribute__((ext_vector_type(4)));

// ---------------- weight prep: transpose + fp16 convert, all layers ----------------
__global__ void wprep_kernel(const float* __restrict__ wq, const float* __restrict__ bq,
                             const float* __restrict__ wk, const float* __restrict__ bk,
                             const float* __restrict__ wv, const float* __restrict__ bv,
                             const float* __restrict__ wskip, const float* __restrict__ bskip,
                             const float* __restrict__ wm, const float* __restrict__ wmsg,
                             const float* __restrict__ we, const float* __restrict__ wcat,
                             const float* __restrict__ emb_w, const float* __restrict__ rbf_w1,
                             const float* __restrict__ rbf_w2, const float* __restrict__ fc_w,
                             _Float16* __restrict__ wb, float* __restrict__ bb)
{
    int idx = blockIdx.x * 256 + threadIdx.x;
    if (idx < 5 * LWH) {
        int l = idx / LWH, r = idx % LWH;
        float val;
        if (r < 212992) {
            int n = r >> 7, kk = r & 127;
            if (n < 512)       val = wq[(size_t)l * 65536 + kk * 512 + n];
            else if (n < 1024) val = wk[(size_t)l * 65536 + kk * 512 + (n - 512)];
            else if (n < 1536) val = wv[(size_t)l * 65536 + kk * 512 + (n - 1024)];
            else               val = wskip[(size_t)l * 16384 + kk * 128 + (n - 1536)];
        } else if (r < 311296) {
            int t = r - 212992; int n = t >> 7, kk = t & 127;
            val = (n < 384) ? wm[(size_t)l * 147456 + kk * 384 + n]
                            : wm[(size_t)l * 147456 + (128 + kk) * 384 + (n - 384)];
        } else if (r < 360448) {
            int t = r - 311296; int n = t >> 7, kk = t & 127;
            val = wm[(size_t)l * 147456 + (256 + kk) * 384 + n];
        } else if (r < 409600) {
            int t = r - 360448; int n = t / 384, kk = t % 384;
            val = wmsg[(size_t)l * 49152 + kk * 128 + n];
        } else if (r < 475136) {
            int t = r - 409600; int n = t >> 7, kk = t & 127;
            val = we[(size_t)l * 65536 + kk * 512 + n];
        } else {
            int t = r - 475136; int n = t >> 9, kk = t & 511;
            val = wcat[(size_t)l * 65536 + kk * 128 + n];
        }
        wb[idx] = (_Float16)val;
    } else if (idx < TOT_H) {
        int t = idx - EX0;
        float val;
        if (t < 12288)      { int n = t / 96, kk = t % 96; val = (kk < FIN) ? emb_w[kk * 128 + n] : 0.f; }
        else if (t < 28672) { int t2 = t - 12288; int n = t2 >> 7, kk = t2 & 127; val = rbf_w1[kk * 128 + n]; }
        else if (t < 45056) { int t2 = t - 28672; int n = t2 >> 7, kk = t2 & 127; val = rbf_w2[kk * 128 + n]; }
        else                { int t2 = t - 45056; int n = t2 >> 7, kk = t2 & 127; val = fc_w[kk * 128 + n]; }
        wb[idx] = (_Float16)val;
    } else if (idx < TOT_ALL) {
        int t = idx - TOT_H;
        int l = t / 1664, n = t % 1664;
        float val;
        if (n < 512)       val = bq[l * 512 + n];
        else if (n < 1024) val = bk[l * 512 + n - 512];
        else if (n < 1536) val = bv[l * 512 + n - 1024];
        else               val = bskip[l * 128 + n - 1536];
        bb[t] = val;
    }
}

// ---------------- x -> fp16 padded to 96 ----------------
__global__ void xpack_kernel(const float* __restrict__ x, _Float16* __restrict__ x16)
{
    int idx = blockIdx.x * 256 + threadIdx.x;
    if (idx >= N_NODES * 96) return;
    int n = idx / 96, kk = idx % 96;
    x16[idx] = (kk < FIN) ? (_Float16)x[n * FIN + kk] : (_Float16)0.f;
}

// ---------------- RBF expansion (fp16 out) ----------------
__global__ void rbf_kernel(const float* __restrict__ eattr, _Float16* __restrict__ rbf)
{
    int idx = blockIdx.x * 256 + threadIdx.x;
    int e = idx >> 7, c = idx & 127;
    float x0 = eattr[e * 3 + 0], x1 = eattr[e * 3 + 1], x2 = eattr[e * 3 + 2];
    float d = sqrtf(x0 * x0 + x1 * x1 + x2 * x2);
    float ctr = (8.0f / 127.0f) * (float)c;
    float t = d - ctr;
    rbf[idx] = (_Float16)expf(-15.875f * t * t);
}

// ---------------- unified fp16 MFMA GEMM ----------------
// C = act(A @ B^T + bias). Tile 128x128, 4 waves (each 32 rows x 128 cols).
// AMODE: 0 = fp16, uniform lda; 1 = fp32, uniform lda; 2 = fp16 quad (row -> (row>>2)*lda + (row&3)*128)
// ACT: 0 none, 1 softplus, 2 silu.  SPLITK: grid.z splits K, fp32 atomicAdd out.
template<int AMODE, int ACT, bool OUT_F32, bool SPLITK>
__global__ __launch_bounds__(256) void gemm16(
    const void* __restrict__ Av, int lda,
    const _Float16* __restrict__ Bt, int ldb, int bkoff,
    const float* __restrict__ bias,
    void* __restrict__ Cv, int ldc, int K)
{
    __shared__ alignas(16) _Float16 As[128 * 40];
    __shared__ alignas(16) _Float16 Bs[128 * 40];
    const int tid = threadIdx.x;
    const int w = tid >> 6, l = tid & 63;
    const int g = l >> 4, c = l & 15;
    const int row0 = blockIdx.x * 128;
    const int col0 = blockIdx.y * 128;
    int k0 = 0, kend = K;
    if (SPLITK) { int ks = K / gridDim.z; k0 = blockIdx.z * ks; kend = k0 + ks; }
    f32x4 acc[2][8] = {};
    for (int kb = k0; kb < kend; kb += 32) {
        __syncthreads();
        #pragma unroll
        for (int i = 0; i < 2; ++i) {
            int p = tid + 256 * i;
            int r = p >> 2, q = p & 3;
            *(uint4*)&Bs[r * 40 + q * 8] =
                *(const uint4*)&Bt[(size_t)(col0 + r) * ldb + bkoff + kb + q * 8];
            if (AMODE == 1) {
                const float* Af = (const float*)Av;
                const float* ap = Af + (size_t)(row0 + r) * lda + kb + q * 8;
                F4 x0 = *(const F4*)ap;
                F4 x1 = *(const F4*)(ap + 4);
                union { _Float16 h[8]; uint4 u; } cv;
                #pragma unroll
                for (int j = 0; j < 4; ++j) { cv.h[j] = (_Float16)x0.v[j]; cv.h[4 + j] = (_Float16)x1.v[j]; }
                *(uint4*)&As[r * 40 + q * 8] = cv.u;
            } else if (AMODE == 2) {
                const _Float16* Ah = (const _Float16*)Av;
                int row = row0 + r;
                *(uint4*)&As[r * 40 + q * 8] =
                    *(const uint4*)&Ah[(size_t)(row >> 2) * lda + (row & 3) * 128 + kb + q * 8];
            } else {
                const _Float16* Ah = (const _Float16*)Av;
                *(uint4*)&As[r * 40 + q * 8] =
                    *(const uint4*)&Ah[(size_t)(row0 + r) * lda + kb + q * 8];
            }
        }
        __syncthreads();
        f16x8 af[2], bf[8];
        #pragma unroll
        for (int mi = 0; mi < 2; ++mi)
            af[mi] = *(const f16x8*)&As[(w * 32 + mi * 16 + c) * 40 + g * 8];
        #pragma unroll
        for (int ni = 0; ni < 8; ++ni)
            bf[ni] = *(const f16x8*)&Bs[(ni * 16 + c) * 40 + g * 8];
        #pragma unroll
        for (int mi = 0; mi < 2; ++mi)
            #pragma unroll
            for (int ni = 0; ni < 8; ++ni)
                acc[mi][ni] = __builtin_amdgcn_mfma_f32_16x16x32_f16(af[mi], bf[ni], acc[mi][ni], 0, 0, 0);
    }
    const bool addb = bias && (!SPLITK || blockIdx.z == 0);
    #pragma unroll
    for (int mi = 0; mi < 2; ++mi)
        #pragma unroll
        for (int ni = 0; ni < 8; ++ni)
            #pragma unroll
            for (int i = 0; i < 4; ++i) {
                int row = row0 + w * 32 + mi * 16 + g * 4 + i;
                int col = col0 + ni * 16 + c;
                float v = acc[mi][ni][i] + (addb ? bias[col] : 0.f);
                if (ACT == 1) v = fmaxf(v, 0.f) + log1pf(expf(-fabsf(v)));
                else if (ACT == 2) v = v / (1.f + expf(-v));
                if (SPLITK)       atomicAdd((float*)Cv + (size_t)row * ldc + col, v);
                else if (OUT_F32) ((float*)Cv)[(size_t)row * ldc + col] = v;
                else              ((_Float16*)Cv)[(size_t)row * ldc + col] = (_Float16)v;
            }
}

// ---------------- combine: t = (P1[dst]+P2[src]+P3+bm) * sigmoid(LN(alpha)) ----------------
__global__ __launch_bounds__(256) void combine_kernel(
    const _Float16* __restrict__ qkvs,   // [2048][1664]
    const _Float16* __restrict__ e16,    // [65536][128]
    const _Float16* __restrict__ p12,    // [8192][768]
    const _Float16* __restrict__ p3,     // [65536][384]
    const float* __restrict__ bm, const float* __restrict__ lag, const float* __restrict__ lab,
    const int* __restrict__ src, const int* __restrict__ dst,
    _Float16* __restrict__ T)            // [65536][384]
{
    const int w = threadIdx.x >> 6, l = threadIdx.x & 63;
    const int r = blockIdx.x * 4 + w;
    const int edge = r >> 2, hh = r & 3;
    const int ni = dst[edge], nj = src[edge];
    const _Float16* qp  = qkvs + (size_t)ni * 1664 + hh * 128;
    const _Float16* kip = qkvs + (size_t)ni * 1664 + 512 + hh * 128;
    const _Float16* kjp = qkvs + (size_t)nj * 1664 + 512 + hh * 128;
    const _Float16* ep  = e16 + (size_t)r * 128;
    const int c2 = l * 2;
    const float ISQ = 0.05103103630798287f; // 1/sqrt(384)
    float q0 = (float)qp[c2], q1 = (float)qp[c2 + 1];
    float a[3][2];
    a[0][0] = q0 * (float)kip[c2] * ISQ;  a[0][1] = q1 * (float)kip[c2 + 1] * ISQ;
    a[1][0] = q0 * (float)kjp[c2] * ISQ;  a[1][1] = q1 * (float)kjp[c2 + 1] * ISQ;
    a[2][0] = q0 * (float)ep[c2] * ISQ;   a[2][1] = q1 * (float)ep[c2 + 1] * ISQ;
    float s1 = 0.f, s2 = 0.f;
    #pragma unroll
    for (int s = 0; s < 3; ++s)
        #pragma unroll
        for (int i = 0; i < 2; ++i) { s1 += a[s][i]; s2 += a[s][i] * a[s][i]; }
    #pragma unroll
    for (int off = 1; off < 64; off <<= 1) {
        s1 += __shfl_xor(s1, off);
        s2 += __shfl_xor(s2, off);
    }
    float mu = s1 * (1.f / 384.f);
    float var = s2 * (1.f / 384.f) - mu * mu;
    float rs = rsqrtf(var + EPSV);
    const _Float16* p1p = p12 + (size_t)(ni * 4 + hh) * 768;
    const _Float16* p2p = p12 + (size_t)(nj * 4 + hh) * 768 + 384;
    const _Float16* p3p = p3 + (size_t)r * C3_;
    _Float16* tp = T + (size_t)r * C3_;
    #pragma unroll
    for (int s = 0; s < 3; ++s) {
        #pragma unroll
        for (int i = 0; i < 2; ++i) {
            int col = s * 128 + c2 + i;
            float z = (a[s][i] - mu) * rs * lag[col] + lab[col];
            float gate = 1.f / (1.f + expf(-z));
            float t = (float)p1p[col] + (float)p2p[col] + (float)p3p[col] + bm[col];
            tp[col] = (_Float16)(t * gate);
        }
    }
}

// ---------------- GEMM2: u = T @ wmsg + bmsg; row-LN(128); scatter-add ----------------
__global__ __launch_bounds__(256) void gemm2_f16(
    const _Float16* __restrict__ A, const _Float16* __restrict__ Bt,
    const float* __restrict__ bmsg, const float* __restrict__ lmg, const float* __restrict__ lmb,
    const int* __restrict__ dst, float* __restrict__ agg)
{
    __shared__ alignas(16) _Float16 As[128 * 40];
    __shared__ alignas(16) _Float16 Bs[128 * 40];
    const int tid = threadIdx.x;
    const int w = tid >> 6, l = tid & 63;
    const int g = l >> 4, c = l & 15;
    const int row0 = blockIdx.x * 128;
    f32x4 acc[2][8] = {};
    for (int kb = 0; kb < 12; ++kb) {
        __syncthreads();
        #pragma unroll
        for (int i = 0; i < 2; ++i) {
            int p = tid + 256 * i;
            int r = p >> 2, q = p & 3;
            *(uint4*)&Bs[r * 40 + q * 8] =
                *(const uint4*)&Bt[(size_t)r * 384 + kb * 32 + q * 8];
            *(uint4*)&As[r * 40 + q * 8] =
                *(const uint4*)&A[(size_t)(row0 + r) * 384 + kb * 32 + q * 8];
        }
        __syncthreads();
        f16x8 af[2], bf[8];
        #pragma unroll
        for (int mi = 0; mi < 2; ++mi)
            af[mi] = *(const f16x8*)&As[(w * 32 + mi * 16 + c) * 40 + g * 8];
        #pragma unroll
        for (int ni = 0; ni < 8; ++ni)
            bf[ni] = *(const f16x8*)&Bs[(ni * 16 + c) * 40 + g * 8];
        #pragma unroll
        for (int mi = 0; mi < 2; ++mi)
            #pragma unroll
            for (int ni = 0; ni < 8; ++ni)
                acc[mi][ni] = __builtin_amdgcn_mfma_f32_16x16x32_f16(af[mi], bf[ni], acc[mi][ni], 0, 0, 0);
    }
    float bz[8], lgv[8], lbv[8];
    #pragma unroll
    for (int ni = 0; ni < 8; ++ni) {
        int colc = ni * 16 + c;
        bz[ni] = bmsg[colc]; lgv[ni] = lmg[colc]; lbv[ni] = lmb[colc];
    }
    #pragma unroll
    for (int mi = 0; mi < 2; ++mi)
        #pragma unroll
        for (int i = 0; i < 4; ++i) {
            float u[8];
            float s1 = 0.f, s2 = 0.f;
            #pragma unroll
            for (int ni = 0; ni < 8; ++ni) {
                u[ni] = acc[mi][ni][i] + bz[ni];
                s1 += u[ni]; s2 += u[ni] * u[ni];
            }
            #pragma unroll
            for (int off = 1; off < 16; off <<= 1) {
                s1 += __shfl_xor(s1, off);
                s2 += __shfl_xor(s2, off);
            }
            float mu = s1 * (1.f / 128.f);
            float var = s2 * (1.f / 128.f) - mu * mu;
            float rs = rsqrtf(var + EPSV);
            int grow = row0 + w * 32 + mi * 16 + g * 4 + i;
            int edge = grow >> 2, hh = grow & 3;
            int nd = dst[edge];
            float* ap = agg + (size_t)nd * HC_ + hh * CC_;
            #pragma unroll
            for (int ni = 0; ni < 8; ++ni) {
                int colc = ni * 16 + c;
                float msg = (u[ni] - mu) * rs * lgv[ni] + lbv[ni];
                atomicAdd(ap + colc, msg);
            }
        }
}

// ---------------- BN stats over nodes (per channel) ----------------
__global__ void bn_stats_kernel(const float* __restrict__ outb,
                                float* __restrict__ mu, float* __restrict__ rv)
{
    int c = blockIdx.x;
    int tid = threadIdx.x;
    float s = 0.f, s2 = 0.f;
    for (int r = tid; r < N_NODES; r += 256) {
        float x = outb[(size_t)r * CC_ + c];
        s += x; s2 += x * x;
    }
    #pragma unroll
    for (int off = 1; off < 64; off <<= 1) {
        s += __shfl_xor(s, off);
        s2 += __shfl_xor(s2, off);
    }
    __shared__ float ls[8];
    int w = tid >> 6, ln = tid & 63;
    if (ln == 0) { ls[w] = s; ls[4 + w] = s2; }
    __syncthreads();
    if (tid == 0) {
        float S = ls[0] + ls[1] + ls[2] + ls[3];
        float S2 = ls[4] + ls[5] + ls[6] + ls[7];
        float m = S * (1.f / N_NODES);
        float var = S2 * (1.f / N_NODES) - m * m;
        mu[c] = m;
        rv[c] = rsqrtf(var + EPSV);
    }
}

// ---------------- BN apply + silu + residual(skip) -> h16 ----------------
__global__ void bn_apply_kernel(const float* __restrict__ outb, const _Float16* __restrict__ qkvs,
                                const float* __restrict__ mu, const float* __restrict__ rv,
                                const float* __restrict__ g, const float* __restrict__ b,
                                _Float16* __restrict__ h16)
{
    int idx = blockIdx.x * 256 + threadIdx.x;
    int n = idx >> 7, c = idx & (CC_ - 1);
    float x = (outb[idx] - mu[c]) * rv[c] * g[c] + b[c];
    x = x / (1.f + expf(-x));
    float skip = (float)qkvs[(size_t)n * 1664 + 1536 + c];
    h16[idx] = (_Float16)(x + skip);
}

// ---------------- output head + batch correction ----------------
__global__ void head_kernel(const float* __restrict__ feat, const float* __restrict__ fcow,
                            const float* __restrict__ fcob, const int* __restrict__ batch,
                            float* __restrict__ out, float* __restrict__ qa_buf,
                            float* __restrict__ qsum, float* __restrict__ cnt)
{
    int n = blockIdx.x * 256 + threadIdx.x;
    float ea = fcob[0], qa = fcob[1];
    for (int j = 0; j < DD; ++j) {
        float f = feat[(size_t)n * DD + j];
        ea += f * fcow[2 * j];
        qa += f * fcow[2 * j + 1];
    }
    out[2 * n] = ea;
    qa_buf[n] = qa;
    int b = batch[n];
    atomicAdd(&qsum[b], qa);
    atomicAdd(&cnt[b], 1.0f);
}

__global__ void final_kernel(const float* __restrict__ qa_buf, const int* __restrict__ batch,
                             const float* __restrict__ qsum, const float* __restrict__ cnt,
                             float* __restrict__ out)
{
    int n = blockIdx.x * 256 + threadIdx.x;
    int b = batch[n];
    out[2 * n + 1] = qa_buf[n] - qsum[b] / cnt[b];
}

// ---------------- launcher ----------------
extern "C" void kernel_launch(void* const* d_in, const int* in_sizes, int n_in,
                              void* d_out, int out_size, void* d_ws, size_t ws_size,
                              hipStream_t stream)
{
    const float* x         = (const float*)d_in[0];
    const float* edge_attr = (const float*)d_in[1];
    const int*   edge_index= (const int*)d_in[2];
    const int*   batch     = (const int*)d_in[3];
    const float* rbf_b1 = (const float*)d_in[7];
    const float* rbf_b2 = (const float*)d_in[9];
    const float* bcat = (const float*)d_in[18];
    const float* bm = (const float*)d_in[20];
    const float* lag = (const float*)d_in[21];
    const float* lab = (const float*)d_in[22];
    const float* bmsg = (const float*)d_in[24];
    const float* lmg = (const float*)d_in[25];
    const float* lmb = (const float*)d_in[26];
    const float* bn_g = (const float*)d_in[27];
    const float* bn_b = (const float*)d_in[28];
    const float* fc_b = (const float*)d_in[32];
    const float* fco_w = (const float*)d_in[33];
    const float* fco_b = (const float*)d_in[34];

    const int* src = edge_index;
    const int* dst = edge_index + NE;

    char* base = (char*)d_ws;
    size_t off = 0;
    auto alloc = [&](size_t bytes) -> char* {
        char* p = base + off;
        off += (bytes + 255) & ~(size_t)255;
        return p;
    };
    _Float16* wbuf   = (_Float16*)alloc((size_t)TOT_H * 2);
    float*    biasb  = (float*)alloc((size_t)5 * 1664 * 4);
    _Float16* x16    = (_Float16*)alloc((size_t)N_NODES * 96 * 2);
    _Float16* h16    = (_Float16*)alloc((size_t)N_NODES * DD * 2);
    _Float16* rbf16  = (_Float16*)alloc((size_t)NE * DD * 2);
    _Float16* tmp16  = (_Float16*)alloc((size_t)NE * DD * 2);
    _Float16* ef16   = (_Float16*)alloc((size_t)NE * DD * 2);
    _Float16* qkvs16 = (_Float16*)alloc((size_t)N_NODES * 1664 * 2);
    _Float16* ebuf16 = (_Float16*)alloc((size_t)NE * HC_ * 2);
    _Float16* p12    = (_Float16*)alloc((size_t)8192 * 768 * 2);
    _Float16* p3     = (_Float16*)alloc((size_t)NE * HH_ * C3_ * 2);
    _Float16* t16    = (_Float16*)alloc((size_t)NE * HH_ * C3_ * 2);
    float* agg    = (float*)alloc((size_t)N_NODES * HC_ * 4);
    float* outb   = (float*)alloc((size_t)N_NODES * CC_ * 4);
    float* featb  = (float*)alloc((size_t)N_NODES * DD * 4);
    float* qa_buf = (float*)alloc((size_t)N_NODES * 4);
    float* mu     = (float*)alloc(CC_ * 4);
    float* rv     = (float*)alloc(CC_ * 4);
    float* qsum   = (float*)alloc((size_t)NB * 2 * 4);
    float* cnt    = qsum + NB;

    // ---- weight prep (all layers) + input packs ----
    wprep_kernel<<<(TOT_ALL + 255) / 256, 256, 0, stream>>>(
        (const float*)d_in[10], (const float*)d_in[11], (const float*)d_in[12], (const float*)d_in[13],
        (const float*)d_in[14], (const float*)d_in[15], (const float*)d_in[29], (const float*)d_in[30],
        (const float*)d_in[19], (const float*)d_in[23], (const float*)d_in[16], (const float*)d_in[17],
        (const float*)d_in[4], (const float*)d_in[6], (const float*)d_in[8], (const float*)d_in[31],
        wbuf, biasb);
    xpack_kernel<<<(N_NODES * 96 + 255) / 256, 256, 0, stream>>>(x, x16);
    rbf_kernel<<<(NE * 128) / 256, 256, 0, stream>>>(edge_attr, rbf16);

    // h = x @ emb + emb_b  (K=96 zero-padded)
    gemm16<0, 0, false, false><<<dim3(16, 1), 256, 0, stream>>>(
        x16, 96, wbuf + OFF_EMBT, 96, 0, (const float*)d_in[5], h16, DD, 96);
    // ef = softplus(rbf@w1+b1) @ w2 + b2
    gemm16<0, 1, false, false><<<dim3(NE / 128, 1), 256, 0, stream>>>(
        rbf16, 128, wbuf + OFF_W1T, 128, 0, rbf_b1, tmp16, 128, 128);
    gemm16<0, 0, false, false><<<dim3(NE / 128, 1), 256, 0, stream>>>(
        tmp16, 128, wbuf + OFF_W2T, 128, 0, rbf_b2, ef16, 128, 128);

    for (int l = 0; l < NL; ++l) {
        const _Float16* lw = wbuf + (size_t)l * LWH;
        const float* bias_l = biasb + (size_t)l * 1664;
        const float* bcat_l = bcat + (size_t)l * CC_;
        const float* bm_l = bm + (size_t)l * C3_;
        const float* lag_l = lag + (size_t)l * C3_;
        const float* lab_l = lab + (size_t)l * C3_;
        const float* bmsg_l = bmsg + (size_t)l * CC_;
        const float* lmg_l = lmg + (size_t)l * CC_;
        const float* lmb_l = lmb + (size_t)l * CC_;
        const float* bng_l = bn_g + (size_t)l * CC_;
        const float* bnb_l = bn_b + (size_t)l * CC_;

        // qkvs = h @ [wq|wk|wv|wskip] + [bq|bk|bv|bskip]
        gemm16<0, 0, false, false><<<dim3(16, 13), 256, 0, stream>>>(
            h16, DD, lw + OFF_QKVST, 128, 0, bias_l, qkvs16, 1664, 128);
        // e = ef @ we
        gemm16<0, 0, false, false><<<dim3(NE / 128, 4), 256, 0, stream>>>(
            ef16, 128, lw + OFF_WET, 128, 0, nullptr, ebuf16, HC_, 128);
        // P1|P2 = v @ [wm_top | wm_mid]   (A = quad view of v inside qkvs)
        gemm16<2, 0, false, false><<<dim3(64, 6), 256, 0, stream>>>(
            qkvs16 + 1024, 1664, lw + OFF_W12T, 128, 0, nullptr, p12, 768, 128);
        // P3 = e @ wm_bot
        gemm16<0, 0, false, false><<<dim3(NE * HH_ / 128, 3), 256, 0, stream>>>(
            ebuf16, 128, lw + OFF_WM3T, 128, 0, nullptr, p3, C3_, 128);

        // t = (P1[dst]+P2[src]+P3+bm) * sigmoid(LN(alpha))
        combine_kernel<<<NE * HH_ / 4, 256, 0, stream>>>(
            qkvs16, ebuf16, p12, p3, bm_l, lag_l, lab_l, src, dst, t16);

        // agg = segment_sum(LN(t@wmsg+bmsg))
        hipMemsetAsync(agg, 0, (size_t)N_NODES * HC_ * sizeof(float), stream);
        gemm2_f16<<<NE * HH_ / 128, 256, 0, stream>>>(
            t16, lw + OFF_WMSGT, bmsg_l, lmg_l, lmb_l, dst, agg);

        // outb = agg @ wcat + bcat (split-K), BN, silu, +skip -> h16
        hipMemsetAsync(outb, 0, (size_t)N_NODES * CC_ * sizeof(float), stream);
        gemm16<1, 0, false, true><<<dim3(16, 1, 4), 256, 0, stream>>>(
            agg, HC_, lw + OFF_WCATT, 512, 0, bcat_l, outb, CC_, 512);
        bn_stats_kernel<<<CC_, 256, 0, stream>>>(outb, mu, rv);
        bn_apply_kernel<<<(N_NODES * CC_) / 256, 256, 0, stream>>>(
            outb, qkvs16, mu, rv, bng_l, bnb_l, h16);
    }

    // feat = silu(h @ fc_w + fc_b)
    gemm16<0, 2, true, false><<<dim3(16, 1), 256, 0, stream>>>(
        h16, DD, wbuf + OFF_FCT, 128, 0, fc_b, featb, DD, 128);

    hipMemsetAsync(qsum, 0, (size_t)NB * 2 * sizeof(float), stream);
    head_kernel<<<N_NODES / 256, 256, 0, stream>>>(featb, fco_w, fco_b, batch,
                                                   (float*)d_out, qa_buf, qsum, cnt);
    final_kernel<<<N_NODES / 256, 256, 0, stream>>>(qa_buf, batch, qsum, cnt, (float*)d_out);
}

// Round 6
// 1075.313 us; speedup vs baseline: 3.9949x; 1.0680x over previous
//
#include <hip/hip_runtime.h>
#include <math.h>

#define N_NODES 2048
#define NE      16384
#define NB      64
#define FIN     92
#define DD      128
#define HH_     4
#define CC_     128
#define HC_     512
#define C3_     384
#define NL      5
#define EPSV    1e-5f

// per-layer packed fp16 weight block offsets (halves)
#define LWH        540672
#define OFF_QKVST  0        // [1664][128]
#define OFF_W12T   212992   // [768][128]
#define OFF_WM3T   311296   // [384][128]
#define OFF_WMSGT  360448   // [128][384]
#define OFF_WET    409600   // [512][128]
#define OFF_WCATT  475136   // [128][512]
#define EX0        (5*LWH)
#define OFF_EMBT   (EX0)            // [128][96]
#define OFF_W1T    (EX0+12288)      // [128][128]
#define OFF_W2T    (EX0+28672)      // [128][128]
#define OFF_FCT    (EX0+45056)      // [128][128]
#define TOT_H      (EX0+61440)
#define TOT_ALL    (TOT_H + 5*1664)

struct alignas(16) F4 { float v[4]; };
typedef _Float16 f16x8 __attribute__((ext_vector_type(8)));
typedef float f32x4 __attribute__((ext_vector_type(4)));

// ---------------- weight prep: transpose + fp16 convert, all layers ----------------
__global__ void wprep_kernel(const float* __restrict__ wq, const float* __restrict__ bq,
                             const float* __restrict__ wk, const float* __restrict__ bk,
                             const float* __restrict__ wv, const float* __restrict__ bv,
                             const float* __restrict__ wskip, const float* __restrict__ bskip,
                             const float* __restrict__ wm, const float* __restrict__ wmsg,
                             const float* __restrict__ we, const float* __restrict__ wcat,
                             const float* __restrict__ emb_w, const float* __restrict__ rbf_w1,
                             const float* __restrict__ rbf_w2, const float* __restrict__ fc_w,
                             _Float16* __restrict__ wb, float* __restrict__ bb)
{
    int idx = blockIdx.x * 256 + threadIdx.x;
    if (idx < 5 * LWH) {
        int l = idx / LWH, r = idx % LWH;
        float val;
        if (r < 212992) {
            int n = r >> 7, kk = r & 127;
            if (n < 512)       val = wq[(size_t)l * 65536 + kk * 512 + n];
            else if (n < 1024) val = wk[(size_t)l * 65536 + kk * 512 + (n - 512)];
            else if (n < 1536) val = wv[(size_t)l * 65536 + kk * 512 + (n - 1024)];
            else               val = wskip[(size_t)l * 16384 + kk * 128 + (n - 1536)];
        } else if (r < 311296) {
            int t = r - 212992; int n = t >> 7, kk = t & 127;
            val = (n < 384) ? wm[(size_t)l * 147456 + kk * 384 + n]
                            : wm[(size_t)l * 147456 + (128 + kk) * 384 + (n - 384)];
        } else if (r < 360448) {
            int t = r - 311296; int n = t >> 7, kk = t & 127;
            val = wm[(size_t)l * 147456 + (256 + kk) * 384 + n];
        } else if (r < 409600) {
            int t = r - 360448; int n = t / 384, kk = t % 384;
            val = wmsg[(size_t)l * 49152 + kk * 128 + n];
        } else if (r < 475136) {
            int t = r - 409600; int n = t >> 7, kk = t & 127;
            val = we[(size_t)l * 65536 + kk * 512 + n];
        } else {
            int t = r - 475136; int n = t >> 9, kk = t & 511;
            val = wcat[(size_t)l * 65536 + kk * 128 + n];
        }
        wb[idx] = (_Float16)val;
    } else if (idx < TOT_H) {
        int t = idx - EX0;
        float val;
        if (t < 12288)      { int n = t / 96, kk = t % 96; val = (kk < FIN) ? emb_w[kk * 128 + n] : 0.f; }
        else if (t < 28672) { int t2 = t - 12288; int n = t2 >> 7, kk = t2 & 127; val = rbf_w1[kk * 128 + n]; }
        else if (t < 45056) { int t2 = t - 28672; int n = t2 >> 7, kk = t2 & 127; val = rbf_w2[kk * 128 + n]; }
        else                { int t2 = t - 45056; int n = t2 >> 7, kk = t2 & 127; val = fc_w[kk * 128 + n]; }
        wb[idx] = (_Float16)val;
    } else if (idx < TOT_ALL) {
        int t = idx - TOT_H;
        int l = t / 1664, n = t % 1664;
        float val;
        if (n < 512)       val = bq[l * 512 + n];
        else if (n < 1024) val = bk[l * 512 + n - 512];
        else if (n < 1536) val = bv[l * 512 + n - 1024];
        else               val = bskip[l * 128 + n - 1536];
        bb[t] = val;
    }
}

// ---------------- x -> fp16 padded to 96 ----------------
__global__ void xpack_kernel(const float* __restrict__ x, _Float16* __restrict__ x16)
{
    int idx = blockIdx.x * 256 + threadIdx.x;
    if (idx >= N_NODES * 96) return;
    int n = idx / 96, kk = idx % 96;
    x16[idx] = (kk < FIN) ? (_Float16)x[n * FIN + kk] : (_Float16)0.f;
}

// ---------------- RBF expansion (fp16 out) ----------------
__global__ void rbf_kernel(const float* __restrict__ eattr, _Float16* __restrict__ rbf)
{
    int idx = blockIdx.x * 256 + threadIdx.x;
    int e = idx >> 7, c = idx & 127;
    float x0 = eattr[e * 3 + 0], x1 = eattr[e * 3 + 1], x2 = eattr[e * 3 + 2];
    float d = sqrtf(x0 * x0 + x1 * x1 + x2 * x2);
    float ctr = (8.0f / 127.0f) * (float)c;
    float t = d - ctr;
    rbf[idx] = (_Float16)expf(-15.875f * t * t);
}

// ---------------- unified fp16 MFMA GEMM ----------------
template<int AMODE, int ACT, bool OUT_F32, bool SPLITK>
__global__ __launch_bounds__(256) void gemm16(
    const void* __restrict__ Av, int lda,
    const _Float16* __restrict__ Bt, int ldb, int bkoff,
    const float* __restrict__ bias,
    void* __restrict__ Cv, int ldc, int K)
{
    __shared__ alignas(16) _Float16 As[128 * 40];
    __shared__ alignas(16) _Float16 Bs[128 * 40];
    const int tid = threadIdx.x;
    const int w = tid >> 6, l = tid & 63;
    const int g = l >> 4, c = l & 15;
    const int row0 = blockIdx.x * 128;
    const int col0 = blockIdx.y * 128;
    int k0 = 0, kend = K;
    if (SPLITK) { int ks = K / gridDim.z; k0 = blockIdx.z * ks; kend = k0 + ks; }
    f32x4 acc[2][8] = {};
    for (int kb = k0; kb < kend; kb += 32) {
        __syncthreads();
        #pragma unroll
        for (int i = 0; i < 2; ++i) {
            int p = tid + 256 * i;
            int r = p >> 2, q = p & 3;
            *(uint4*)&Bs[r * 40 + q * 8] =
                *(const uint4*)&Bt[(size_t)(col0 + r) * ldb + bkoff + kb + q * 8];
            if (AMODE == 1) {
                const float* Af = (const float*)Av;
                const float* ap = Af + (size_t)(row0 + r) * lda + kb + q * 8;
                F4 x0 = *(const F4*)ap;
                F4 x1 = *(const F4*)(ap + 4);
                union { _Float16 h[8]; uint4 u; } cv;
                #pragma unroll
                for (int j = 0; j < 4; ++j) { cv.h[j] = (_Float16)x0.v[j]; cv.h[4 + j] = (_Float16)x1.v[j]; }
                *(uint4*)&As[r * 40 + q * 8] = cv.u;
            } else if (AMODE == 2) {
                const _Float16* Ah = (const _Float16*)Av;
                int row = row0 + r;
                *(uint4*)&As[r * 40 + q * 8] =
                    *(const uint4*)&Ah[(size_t)(row >> 2) * lda + (row & 3) * 128 + kb + q * 8];
            } else {
                const _Float16* Ah = (const _Float16*)Av;
                *(uint4*)&As[r * 40 + q * 8] =
                    *(const uint4*)&Ah[(size_t)(row0 + r) * lda + kb + q * 8];
            }
        }
        __syncthreads();
        f16x8 af[2], bf[8];
        #pragma unroll
        for (int mi = 0; mi < 2; ++mi)
            af[mi] = *(const f16x8*)&As[(w * 32 + mi * 16 + c) * 40 + g * 8];
        #pragma unroll
        for (int ni = 0; ni < 8; ++ni)
            bf[ni] = *(const f16x8*)&Bs[(ni * 16 + c) * 40 + g * 8];
        #pragma unroll
        for (int mi = 0; mi < 2; ++mi)
            #pragma unroll
            for (int ni = 0; ni < 8; ++ni)
                acc[mi][ni] = __builtin_amdgcn_mfma_f32_16x16x32_f16(af[mi], bf[ni], acc[mi][ni], 0, 0, 0);
    }
    const bool addb = bias && (!SPLITK || blockIdx.z == 0);
    #pragma unroll
    for (int mi = 0; mi < 2; ++mi)
        #pragma unroll
        for (int ni = 0; ni < 8; ++ni)
            #pragma unroll
            for (int i = 0; i < 4; ++i) {
                int row = row0 + w * 32 + mi * 16 + g * 4 + i;
                int col = col0 + ni * 16 + c;
                float v = acc[mi][ni][i] + (addb ? bias[col] : 0.f);
                if (ACT == 1) v = fmaxf(v, 0.f) + log1pf(expf(-fabsf(v)));
                else if (ACT == 2) v = v / (1.f + expf(-v));
                if (SPLITK)       atomicAdd((float*)Cv + (size_t)row * ldc + col, v);
                else if (OUT_F32) ((float*)Cv)[(size_t)row * ldc + col] = v;
                else              ((_Float16*)Cv)[(size_t)row * ldc + col] = (_Float16)v;
            }
}

// ---------------- fused edge kernel: P3 + gate + GEMM2 + LN + scatter ----------------
// Per block: 16 edges = 64 edge-head rows. 256 threads = 4 waves.
// Never materializes p3 / t16 in HBM.
#define EB2 16
#define RW2 64

__global__ __launch_bounds__(256) void fused_edge_kernel(
    const _Float16* __restrict__ qkvs,   // [2048][1664]
    const _Float16* __restrict__ e16,    // [65536][128]
    const _Float16* __restrict__ p12,    // [8192][768]
    const _Float16* __restrict__ wm3T,   // [384][128]
    const _Float16* __restrict__ wmsgT,  // [128][384]
    const float* __restrict__ bm, const float* __restrict__ lag, const float* __restrict__ lab,
    const float* __restrict__ bmsg, const float* __restrict__ lmg, const float* __restrict__ lmb,
    const int* __restrict__ src, const int* __restrict__ dst,
    float* __restrict__ agg)
{
    __shared__ alignas(16) _Float16 Sq [RW2 * 136];
    __shared__ alignas(16) _Float16 Ski[RW2 * 136];
    __shared__ alignas(16) _Float16 Skj[RW2 * 136];
    __shared__ alignas(16) _Float16 St [RW2 * 40];   // p3 chunk -> t chunk (also phase-1 reduce buf)
    __shared__ alignas(16) _Float16 Bs3[32 * 136];
    __shared__ alignas(16) _Float16 Bsg[128 * 40];
    __shared__ float2 murs[RW2];
    __shared__ int dstn[EB2], srcn[EB2];

    const int tid = threadIdx.x;
    const int w = tid >> 6, l = tid & 63;
    const int g = l >> 4, c = l & 15;
    const int e0 = blockIdx.x * EB2;
    const int row0 = blockIdx.x * RW2;
    const float ISQ = 0.05103103630798287f;  // 1/sqrt(384)

    if (tid < EB2) { dstn[tid] = dst[e0 + tid]; srcn[tid] = src[e0 + tid]; }

    // P3 A-fragments: e rows are contiguous; same frags reused for every chunk.
    f16x8 af3[4];
    {
        const _Float16* ep = e16 + (size_t)(row0 + w * 16 + c) * 128;
        #pragma unroll
        for (int ks = 0; ks < 4; ++ks) af3[ks] = *(const f16x8*)(ep + ks * 32 + g * 8);
    }
    __syncthreads();

    // ---- phase 1: stage q/ki/kj tiles + per-row LN stats of alpha ----
    {
        int r = tid & 63, piece = tid >> 6;
        int el = r >> 2, hh = r & 3;
        int ni = dstn[el], nj = srcn[el];
        const _Float16* qp  = qkvs + (size_t)ni * 1664 + hh * 128 + piece * 32;
        const _Float16* kip = qkvs + (size_t)ni * 1664 + 512 + hh * 128 + piece * 32;
        const _Float16* kjp = qkvs + (size_t)nj * 1664 + 512 + hh * 128 + piece * 32;
        const _Float16* ep  = e16 + (size_t)(row0 + r) * 128 + piece * 32;
        float s1 = 0.f, s2 = 0.f;
        #pragma unroll
        for (int v = 0; v < 4; ++v) {
            f16x8 qv  = *(const f16x8*)(qp + v * 8);
            f16x8 kiv = *(const f16x8*)(kip + v * 8);
            f16x8 kjv = *(const f16x8*)(kjp + v * 8);
            f16x8 ev  = *(const f16x8*)(ep + v * 8);
            *(f16x8*)&Sq [r * 136 + piece * 32 + v * 8] = qv;
            *(f16x8*)&Ski[r * 136 + piece * 32 + v * 8] = kiv;
            *(f16x8*)&Skj[r * 136 + piece * 32 + v * 8] = kjv;
            #pragma unroll
            for (int j = 0; j < 8; ++j) {
                float q = (float)qv[j];
                float a0 = q * (float)kiv[j] * ISQ;
                float a1 = q * (float)kjv[j] * ISQ;
                float a2 = q * (float)ev[j] * ISQ;
                s1 += a0 + a1 + a2;
                s2 += a0 * a0 + a1 * a1 + a2 * a2;
            }
        }
        float2* red = (float2*)St;
        red[piece * 64 + r] = make_float2(s1, s2);
    }
    __syncthreads();
    if (tid < 64) {
        float2* red = (float2*)St;
        float S1 = 0.f, S2 = 0.f;
        #pragma unroll
        for (int p = 0; p < 4; ++p) { float2 v = red[p * 64 + tid]; S1 += v.x; S2 += v.y; }
        float mu = S1 * (1.f / 384.f);
        float var = S2 * (1.f / 384.f) - mu * mu;
        murs[tid] = make_float2(mu, rsqrtf(var + EPSV));
    }
    __syncthreads();

    // ---- chunk loop over K=384 in 32-col chunks ----
    f32x4 acc2[8] = {};
    for (int ck = 0; ck < 12; ++ck) {
        // stage B panels (L2-hot weights)
        #pragma unroll
        for (int i = 0; i < 2; ++i) {
            int p = tid + 256 * i;
            int col = p >> 4, q8 = p & 15;
            *(f16x8*)&Bs3[col * 136 + q8 * 8] =
                *(const f16x8*)&wm3T[(size_t)(ck * 32 + col) * 128 + q8 * 8];
        }
        #pragma unroll
        for (int i = 0; i < 2; ++i) {
            int p = tid + 256 * i;
            int col = p >> 2, q4 = p & 3;
            *(f16x8*)&Bsg[col * 40 + q4 * 8] =
                *(const f16x8*)&wmsgT[(size_t)col * 384 + ck * 32 + q4 * 8];
        }
        __syncthreads();

        // P3 chunk: wave w -> m-tile w (rows w*16..), nt 0..1 (32 cols)
        f32x4 a3[2] = {};
        #pragma unroll
        for (int ks = 0; ks < 4; ++ks) {
            #pragma unroll
            for (int nt = 0; nt < 2; ++nt) {
                f16x8 bf = *(const f16x8*)&Bs3[(nt * 16 + c) * 136 + ks * 32 + g * 8];
                a3[nt] = __builtin_amdgcn_mfma_f32_16x16x32_f16(af3[ks], bf, a3[nt], 0, 0, 0);
            }
        }
        #pragma unroll
        for (int nt = 0; nt < 2; ++nt)
            #pragma unroll
            for (int i = 0; i < 4; ++i)
                St[(w * 16 + g * 4 + i) * 40 + nt * 16 + c] = (_Float16)a3[nt][i];
        __syncthreads();

        // t-build in place: t = (P1[dst]+P2[src]+P3+bm) * sigmoid(LN(alpha))
        {
            int r = tid >> 2, cp = tid & 3;
            int el = r >> 2, hh = r & 3;
            int kk0 = ck * 32 + cp * 8;
            int s = kk0 >> 7, cc0 = kk0 & 127;
            float2 mr = murs[r];
            f16x8 p1v = *(const f16x8*)&p12[((size_t)dstn[el] * 4 + hh) * 768 + kk0];
            f16x8 p2v = *(const f16x8*)&p12[((size_t)srcn[el] * 4 + hh) * 768 + 384 + kk0];
            f16x8 qv = *(const f16x8*)&Sq[r * 136 + cc0];
            f16x8 sv;
            if (s == 0)      sv = *(const f16x8*)&Ski[r * 136 + cc0];
            else if (s == 1) sv = *(const f16x8*)&Skj[r * 136 + cc0];
            else             sv = *(const f16x8*)&e16[(size_t)(row0 + r) * 128 + cc0];
            f16x8 p3v = *(const f16x8*)&St[r * 40 + cp * 8];
            F4 lg0 = *(const F4*)&lag[kk0], lg1 = *(const F4*)&lag[kk0 + 4];
            F4 lb0 = *(const F4*)&lab[kk0], lb1 = *(const F4*)&lab[kk0 + 4];
            F4 bm0 = *(const F4*)&bm[kk0],  bm1 = *(const F4*)&bm[kk0 + 4];
            f16x8 tv;
            #pragma unroll
            for (int j = 0; j < 8; ++j) {
                float aval = (float)qv[j] * (float)sv[j] * ISQ;
                float lgv = (j < 4) ? lg0.v[j] : lg1.v[j - 4];
                float lbv = (j < 4) ? lb0.v[j] : lb1.v[j - 4];
                float bmv = (j < 4) ? bm0.v[j] : bm1.v[j - 4];
                float z = (aval - mr.x) * mr.y * lgv + lbv;
                float gate = 1.f / (1.f + expf(-z));
                float t = (float)p1v[j] + (float)p2v[j] + (float)p3v[j] + bmv;
                tv[j] = (_Float16)(t * gate);
            }
            *(f16x8*)&St[r * 40 + cp * 8] = tv;
        }
        __syncthreads();

        // GEMM2 accumulate: wave w -> m-tile w, all 8 n-tiles
        {
            f16x8 af2 = *(const f16x8*)&St[(w * 16 + c) * 40 + g * 8];
            #pragma unroll
            for (int ni = 0; ni < 8; ++ni) {
                f16x8 bf = *(const f16x8*)&Bsg[(ni * 16 + c) * 40 + g * 8];
                acc2[ni] = __builtin_amdgcn_mfma_f32_16x16x32_f16(af2, bf, acc2[ni], 0, 0, 0);
            }
        }
        __syncthreads();
    }

    // ---- epilogue: +bmsg, row-LN(128), scatter-add ----
    float bz[8], lgv2[8], lbv2[8];
    #pragma unroll
    for (int ni = 0; ni < 8; ++ni) {
        int colc = ni * 16 + c;
        bz[ni] = bmsg[colc]; lgv2[ni] = lmg[colc]; lbv2[ni] = lmb[colc];
    }
    #pragma unroll
    for (int i = 0; i < 4; ++i) {
        float u[8];
        float s1 = 0.f, s2 = 0.f;
        #pragma unroll
        for (int ni = 0; ni < 8; ++ni) {
            u[ni] = acc2[ni][i] + bz[ni];
            s1 += u[ni]; s2 += u[ni] * u[ni];
        }
        #pragma unroll
        for (int off = 1; off < 16; off <<= 1) {
            s1 += __shfl_xor(s1, off);
            s2 += __shfl_xor(s2, off);
        }
        float mu = s1 * (1.f / 128.f);
        float var = s2 * (1.f / 128.f) - mu * mu;
        float rs = rsqrtf(var + EPSV);
        int r = w * 16 + g * 4 + i;
        int el = r >> 2, hh = r & 3;
        int nd = dstn[el];
        float* ap = agg + (size_t)nd * HC_ + hh * CC_;
        #pragma unroll
        for (int ni = 0; ni < 8; ++ni) {
            float msg = (u[ni] - mu) * rs * lgv2[ni] + lbv2[ni];
            atomicAdd(ap + ni * 16 + c, msg);
        }
    }
}

// ---------------- BN stats over nodes (per channel) ----------------
__global__ void bn_stats_kernel(const float* __restrict__ outb,
                                float* __restrict__ mu, float* __restrict__ rv)
{
    int c = blockIdx.x;
    int tid = threadIdx.x;
    float s = 0.f, s2 = 0.f;
    for (int r = tid; r < N_NODES; r += 256) {
        float x = outb[(size_t)r * CC_ + c];
        s += x; s2 += x * x;
    }
    #pragma unroll
    for (int off = 1; off < 64; off <<= 1) {
        s += __shfl_xor(s, off);
        s2 += __shfl_xor(s2, off);
    }
    __shared__ float ls[8];
    int w = tid >> 6, ln = tid & 63;
    if (ln == 0) { ls[w] = s; ls[4 + w] = s2; }
    __syncthreads();
    if (tid == 0) {
        float S = ls[0] + ls[1] + ls[2] + ls[3];
        float S2 = ls[4] + ls[5] + ls[6] + ls[7];
        float m = S * (1.f / N_NODES);
        float var = S2 * (1.f / N_NODES) - m * m;
        mu[c] = m;
        rv[c] = rsqrtf(var + EPSV);
    }
}

// ---------------- BN apply + silu + residual(skip) -> h16 ----------------
__global__ void bn_apply_kernel(const float* __restrict__ outb, const _Float16* __restrict__ qkvs,
                                const float* __restrict__ mu, const float* __restrict__ rv,
                                const float* __restrict__ g, const float* __restrict__ b,
                                _Float16* __restrict__ h16)
{
    int idx = blockIdx.x * 256 + threadIdx.x;
    int n = idx >> 7, c = idx & (CC_ - 1);
    float x = (outb[idx] - mu[c]) * rv[c] * g[c] + b[c];
    x = x / (1.f + expf(-x));
    float skip = (float)qkvs[(size_t)n * 1664 + 1536 + c];
    h16[idx] = (_Float16)(x + skip);
}

// ---------------- output head + batch correction ----------------
__global__ void head_kernel(const float* __restrict__ feat, const float* __restrict__ fcow,
                            const float* __restrict__ fcob, const int* __restrict__ batch,
                            float* __restrict__ out, float* __restrict__ qa_buf,
                            float* __restrict__ qsum, float* __restrict__ cnt)
{
    int n = blockIdx.x * 256 + threadIdx.x;
    float ea = fcob[0], qa = fcob[1];
    for (int j = 0; j < DD; ++j) {
        float f = feat[(size_t)n * DD + j];
        ea += f * fcow[2 * j];
        qa += f * fcow[2 * j + 1];
    }
    out[2 * n] = ea;
    qa_buf[n] = qa;
    int b = batch[n];
    atomicAdd(&qsum[b], qa);
    atomicAdd(&cnt[b], 1.0f);
}

__global__ void final_kernel(const float* __restrict__ qa_buf, const int* __restrict__ batch,
                             const float* __restrict__ qsum, const float* __restrict__ cnt,
                             float* __restrict__ out)
{
    int n = blockIdx.x * 256 + threadIdx.x;
    int b = batch[n];
    out[2 * n + 1] = qa_buf[n] - qsum[b] / cnt[b];
}

// ---------------- launcher ----------------
extern "C" void kernel_launch(void* const* d_in, const int* in_sizes, int n_in,
                              void* d_out, int out_size, void* d_ws, size_t ws_size,
                              hipStream_t stream)
{
    const float* x         = (const float*)d_in[0];
    const float* edge_attr = (const float*)d_in[1];
    const int*   edge_index= (const int*)d_in[2];
    const int*   batch     = (const int*)d_in[3];
    const float* rbf_b1 = (const float*)d_in[7];
    const float* rbf_b2 = (const float*)d_in[9];
    const float* bcat = (const float*)d_in[18];
    const float* bm = (const float*)d_in[20];
    const float* lag = (const float*)d_in[21];
    const float* lab = (const float*)d_in[22];
    const float* bmsg = (const float*)d_in[24];
    const float* lmg = (const float*)d_in[25];
    const float* lmb = (const float*)d_in[26];
    const float* bn_g = (const float*)d_in[27];
    const float* bn_b = (const float*)d_in[28];
    const float* fc_b = (const float*)d_in[32];
    const float* fco_w = (const float*)d_in[33];
    const float* fco_b = (const float*)d_in[34];

    const int* src = edge_index;
    const int* dst = edge_index + NE;

    char* base = (char*)d_ws;
    size_t off = 0;
    auto alloc = [&](size_t bytes) -> char* {
        char* p = base + off;
        off += (bytes + 255) & ~(size_t)255;
        return p;
    };
    _Float16* wbuf   = (_Float16*)alloc((size_t)TOT_H * 2);
    float*    biasb  = (float*)alloc((size_t)5 * 1664 * 4);
    _Float16* x16    = (_Float16*)alloc((size_t)N_NODES * 96 * 2);
    _Float16* h16    = (_Float16*)alloc((size_t)N_NODES * DD * 2);
    _Float16* rbf16  = (_Float16*)alloc((size_t)NE * DD * 2);
    _Float16* tmp16  = (_Float16*)alloc((size_t)NE * DD * 2);
    _Float16* ef16   = (_Float16*)alloc((size_t)NE * DD * 2);
    _Float16* qkvs16 = (_Float16*)alloc((size_t)N_NODES * 1664 * 2);
    _Float16* ebuf16 = (_Float16*)alloc((size_t)NE * HC_ * 2);
    _Float16* p12    = (_Float16*)alloc((size_t)8192 * 768 * 2);
    float* agg    = (float*)alloc((size_t)N_NODES * HC_ * 4);
    float* outb   = (float*)alloc((size_t)N_NODES * CC_ * 4);
    float* featb  = (float*)alloc((size_t)N_NODES * DD * 4);
    float* qa_buf = (float*)alloc((size_t)N_NODES * 4);
    float* mu     = (float*)alloc(CC_ * 4);
    float* rv     = (float*)alloc(CC_ * 4);
    float* qsum   = (float*)alloc((size_t)NB * 2 * 4);
    float* cnt    = qsum + NB;

    // ---- weight prep (all layers) + input packs ----
    wprep_kernel<<<(TOT_ALL + 255) / 256, 256, 0, stream>>>(
        (const float*)d_in[10], (const float*)d_in[11], (const float*)d_in[12], (const float*)d_in[13],
        (const float*)d_in[14], (const float*)d_in[15], (const float*)d_in[29], (const float*)d_in[30],
        (const float*)d_in[19], (const float*)d_in[23], (const float*)d_in[16], (const float*)d_in[17],
        (const float*)d_in[4], (const float*)d_in[6], (const float*)d_in[8], (const float*)d_in[31],
        wbuf, biasb);
    xpack_kernel<<<(N_NODES * 96 + 255) / 256, 256, 0, stream>>>(x, x16);
    rbf_kernel<<<(NE * 128) / 256, 256, 0, stream>>>(edge_attr, rbf16);

    // h = x @ emb + emb_b  (K=96 zero-padded)
    gemm16<0, 0, false, false><<<dim3(16, 1), 256, 0, stream>>>(
        x16, 96, wbuf + OFF_EMBT, 96, 0, (const float*)d_in[5], h16, DD, 96);
    // ef = softplus(rbf@w1+b1) @ w2 + b2
    gemm16<0, 1, false, false><<<dim3(NE / 128, 1), 256, 0, stream>>>(
        rbf16, 128, wbuf + OFF_W1T, 128, 0, rbf_b1, tmp16, 128, 128);
    gemm16<0, 0, false, false><<<dim3(NE / 128, 1), 256, 0, stream>>>(
        tmp16, 128, wbuf + OFF_W2T, 128, 0, rbf_b2, ef16, 128, 128);

    for (int l = 0; l < NL; ++l) {
        const _Float16* lw = wbuf + (size_t)l * LWH;
        const float* bias_l = biasb + (size_t)l * 1664;
        const float* bcat_l = bcat + (size_t)l * CC_;
        const float* bm_l = bm + (size_t)l * C3_;
        const float* lag_l = lag + (size_t)l * C3_;
        const float* lab_l = lab + (size_t)l * C3_;
        const float* bmsg_l = bmsg + (size_t)l * CC_;
        const float* lmg_l = lmg + (size_t)l * CC_;
        const float* lmb_l = lmb + (size_t)l * CC_;
        const float* bng_l = bn_g + (size_t)l * CC_;
        const float* bnb_l = bn_b + (size_t)l * CC_;

        // qkvs = h @ [wq|wk|wv|wskip] + [bq|bk|bv|bskip]
        gemm16<0, 0, false, false><<<dim3(16, 13), 256, 0, stream>>>(
            h16, DD, lw + OFF_QKVST, 128, 0, bias_l, qkvs16, 1664, 128);
        // e = ef @ we
        gemm16<0, 0, false, false><<<dim3(NE / 128, 4), 256, 0, stream>>>(
            ef16, 128, lw + OFF_WET, 128, 0, nullptr, ebuf16, HC_, 128);
        // P1|P2 = v @ [wm_top | wm_mid]
        gemm16<2, 0, false, false><<<dim3(64, 6), 256, 0, stream>>>(
            qkvs16 + 1024, 1664, lw + OFF_W12T, 128, 0, nullptr, p12, 768, 128);

        // fused: P3 + gate + GEMM2 + row-LN + segment scatter
        hipMemsetAsync(agg, 0, (size_t)N_NODES * HC_ * sizeof(float), stream);
        fused_edge_kernel<<<NE / EB2, 256, 0, stream>>>(
            qkvs16, ebuf16, p12, lw + OFF_WM3T, lw + OFF_WMSGT,
            bm_l, lag_l, lab_l, bmsg_l, lmg_l, lmb_l, src, dst, agg);

        // outb = agg @ wcat + bcat (split-K), BN, silu, +skip -> h16
        hipMemsetAsync(outb, 0, (size_t)N_NODES * CC_ * sizeof(float), stream);
        gemm16<1, 0, false, true><<<dim3(16, 1, 4), 256, 0, stream>>>(
            agg, HC_, lw + OFF_WCATT, 512, 0, bcat_l, outb, CC_, 512);
        bn_stats_kernel<<<CC_, 256, 0, stream>>>(outb, mu, rv);
        bn_apply_kernel<<<(N_NODES * CC_) / 256, 256, 0, stream>>>(
            outb, qkvs16, mu, rv, bng_l, bnb_l, h16);
    }

    // feat = silu(h @ fc_w + fc_b)
    gemm16<0, 2, true, false><<<dim3(16, 1), 256, 0, stream>>>(
        h16, DD, wbuf + OFF_FCT, 128, 0, fc_b, featb, DD, 128);

    hipMemsetAsync(qsum, 0, (size_t)NB * 2 * sizeof(float), stream);
    head_kernel<<<N_NODES / 256, 256, 0, stream>>>(featb, fco_w, fco_b, batch,
                                                   (float*)d_out, qa_buf, qsum, cnt);
    final_kernel<<<N_NODES / 256, 256, 0, stream>>>(qa_buf, batch, qsum, cnt, (float*)d_out);
}